// Round 3
// baseline (1717.596 us; speedup 1.0000x reference)
//
#include <hip/hip_runtime.h>

// ---------------------------------------------------------------------------
// Encoder: feature/temporal regression + temporal-decay LSTM scan + L1 loss
// B=512 T=128 F=128 H=256.  Outputs: h[512,256], c[512,256], loss (fp32).
//
// R2 -> R3 (kscan only):
//  1. Register-prefetch pipeline: x(t+1), g(t+1), loss v/m(t+1) are loaded
//     AFTER the acquire fence of step t and consumed at step t+1, so the
//     fence's vmcnt(0) drain never waits on cold HBM loads and the x-half
//     MFMA runs before the poll (off the critical chain).
//  2. Per-producer flag lines (monotone store of t+1, no RMW; no same-line
//     fetch_add serialization). All 256 threads poll (lane tid&7 covers the
//     8 producers), per-wave acquire fence -> post-poll barrier deleted.
//     2 barriers/step instead of 3.
//  3. Loss MFMA (h x out_W) K-split across the 4 waves (2 chunks each),
//     partial C exchanged through LDS on the existing gate barrier; loss
//     |v-out|*m*dinv computed by all 256 threads in the cell phase. Removes
//     the wave-0 imbalance that every gate barrier waited on.
// ---------------------------------------------------------------------------

typedef _Float16 f16;
typedef _Float16 half8 __attribute__((ext_vector_type(8)));
typedef float f32x4 __attribute__((ext_vector_type(4)));

#define B_ 512
#define T_ 128
#define F_ 128
#define H_ 256
#define NSTEP 127
#define KP 520     // padded LDS row stride (elems) for W slice
#define OWP 264    // padded LDS row stride for out_W slice
#define FLAG_STRIDE 16   // dwords: one 64B line per producer WG

__device__ __forceinline__ float sigm(float x){ return 1.f/(1.f + __expf(-x)); }
__device__ __forceinline__ float tanh_(float x){
  float e = __expf(-2.f*fabsf(x));
  float t = (1.f - e)/(1.f + e);
  return x >= 0.f ? t : -t;
}

// ---------------------------------------------------------------------------
__global__ void kprep(const float* __restrict__ Wih, const float* __restrict__ Whh,
                      const float* __restrict__ outW,
                      const float* __restrict__ featW, const float* __restrict__ tempW,
                      const float* __restrict__ decW,
                      f16* __restrict__ Wt, f16* __restrict__ oWh,
                      float* __restrict__ fWT, float* __restrict__ tWm,
                      float* __restrict__ dWT, unsigned int* __restrict__ flags,
                      float* __restrict__ accums)
{
  int idx = blockIdx.x*256 + threadIdx.x;
  int stride = gridDim.x*256;
  // W_cat[zc][k]: k<256 -> W_ih[zc][k] (inp = [values_hat, masks]); k>=256 -> W_hh
  for (int i = idx; i < 1024*512; i += stride){
    int zc = i >> 9, k = i & 511;
    float w = (k < 256) ? Wih[zc*256 + k] : Whh[zc*256 + k - 256];
    Wt[i] = (f16)w;
  }
  for (int i = idx; i < 128*256; i += stride) oWh[i] = (f16)outW[i];
  // fWT[g][f] = feat_W[f][g] with diag zeroed (einsum 'btf,gf->btg' masked)
  for (int i = idx; i < 128*128; i += stride){
    int g = i >> 7, f = i & 127;
    fWT[i] = (f == g) ? 0.f : featW[f*128 + g];
  }
  for (int i = idx; i < 128*128; i += stride){
    int t = i >> 7, s = i & 127;
    tWm[i] = (s == t) ? 0.f : tempW[i];
  }
  // dWT[f][h] = decay_W[h][f]
  for (int i = idx; i < 128*256; i += stride){
    int f = i >> 8, h = i & 255;
    dWT[i] = decW[h*128 + f];
  }
  for (int i = idx; i < 256*FLAG_STRIDE; i += stride) flags[i] = 0u;
  if (idx < 2) accums[idx] = 0.f;
}

// ---------------------------------------------------------------------------
__global__ __launch_bounds__(256) void kdenom(const float* __restrict__ masks,
                                              float* __restrict__ dinv)
{
  int t = blockIdx.x;
  __shared__ float red[256];
  float s = 0.f;
  for (int i = threadIdx.x; i < B_*F_; i += 256){
    int b = i >> 7, f = i & 127;
    s += masks[((size_t)b << 14) + (t << 7) + f];
  }
  red[threadIdx.x] = s; __syncthreads();
  for (int o = 128; o > 0; o >>= 1){
    if (threadIdx.x < o) red[threadIdx.x] += red[threadIdx.x + o];
    __syncthreads();
  }
  if (threadIdx.x == 0) dinv[t] = 1.f/(red[0] + 1e-5f);
}

// ---------------------------------------------------------------------------
// values_hat: vhat[b,t,f] = sum_g v[b,t,g]*fWT[g][f] + sum_s v[b,s,f]*tWm[t][s]
//                           + feat_b[f] + temp_b[t]
// x = v*m + vhat*(1-m); x_all[t][b][0:128]=x, [128:256]=m
__global__ __launch_bounds__(256) void k1(
    const float* __restrict__ values, const float* __restrict__ masks,
    const float* __restrict__ fWT, const float* __restrict__ tWm,
    const float* __restrict__ featb, const float* __restrict__ tempb,
    f16* __restrict__ x_all)
{
  __shared__ float vbuf[128][128];   // 64 KB, 2 blocks/CU
  const int b = blockIdx.x, tid = threadIdx.x;
  const float* vb = values + ((size_t)b << 14);
  for (int i = tid; i < 128*128; i += 256) (&vbuf[0][0])[i] = vb[i];
  __syncthreads();
  const int f = tid & 127, th = tid >> 7;
  const float fb = featb[f];
  for (int tt = 0; tt < 4; ++tt){
    const int t0 = th*64 + tt*16;
    float acc[16];
#pragma unroll
    for (int i = 0; i < 16; ++i) acc[i] = 0.f;
    for (int g = 0; g < 128; ++g){
      float w = fWT[(g<<7) + f];
#pragma unroll
      for (int i = 0; i < 16; ++i) acc[i] += vbuf[t0+i][g] * w;
    }
    for (int s = 0; s < 128; ++s){
      float v = vbuf[s][f];
#pragma unroll
      for (int i = 0; i < 16; ++i) acc[i] += v * tWm[((t0+i)<<7) + s];
    }
#pragma unroll
    for (int i = 0; i < 16; ++i){
      int t = t0 + i;
      float vh = acc[i] + fb + tempb[t];
      float m = masks[((size_t)b << 14) + (t << 7) + f];
      float v = vbuf[t][f];
      float x = v*m + vh*(1.f - m);
      size_t o = (((size_t)t << 9) + b) << 8;
      x_all[o + f] = (f16)x;
      x_all[o + 128 + f] = (f16)m;
    }
  }
}

// ---------------------------------------------------------------------------
__global__ __launch_bounds__(256) void k2(
    const float* __restrict__ deltas, const float* __restrict__ dWT,
    const float* __restrict__ decb, f16* __restrict__ g_all)
{
  __shared__ float dbuf[128][128];
  const int b = blockIdx.x, tid = threadIdx.x;
  const float* dp = deltas + ((size_t)b << 14);
  for (int i = tid; i < 128*128; i += 256) (&dbuf[0][0])[i] = dp[i];
  __syncthreads();
  const float bias = decb[tid];
  for (int tt = 0; tt < 8; ++tt){
    float acc[16];
#pragma unroll
    for (int i = 0; i < 16; ++i) acc[i] = 0.f;
    for (int fch = 0; fch < 128; ++fch){
      float w = dWT[(fch<<8) + tid];
#pragma unroll
      for (int i = 0; i < 16; ++i) acc[i] += dbuf[tt*16+i][fch] * w;
    }
#pragma unroll
    for (int i = 0; i < 16; ++i){
      int t = tt*16 + i;
      float gv = __expf(-fabsf(acc[i] + bias));
      g_all[((((size_t)t << 9) + b) << 8) + tid] = (f16)gv;
    }
  }
}

// ---------------------------------------------------------------------------
// Persistent scan. grid=256: gid=blockIdx&31 (row tile, 16 rows), q=blockIdx>>5
// (col chunk, 32 h-cols => 128 z-cols across 4 gates). 1 WG/CU (LDS-forced).
// Group {gid, gid+32, ..., gid+224} lands on one XCD under round-robin
// blockIdx->XCD mapping (all ≡ gid mod 8) -> same-XCD L2 is the coherence
// point for h_buf; one acquire fence per wave per step invalidates L1.
__global__ __launch_bounds__(256, 1) void kscan(
    const f16* __restrict__ x_all, const f16* __restrict__ g_all,
    const f16* __restrict__ Wt, const f16* __restrict__ oWh,
    const float* __restrict__ bih, const float* __restrict__ bhh,
    const float* __restrict__ outb,
    const float* __restrict__ values, const float* __restrict__ masks,
    const float* __restrict__ dinv,
    f16* __restrict__ h_buf, unsigned int* __restrict__ flags,
    float* __restrict__ loss_accum, float* __restrict__ d_out)
{
  extern __shared__ char smem[];
  f16* Wl  = (f16*)smem;                                    // [128][KP]
  f16* oWl = (f16*)(smem + 128*KP*2);                       // [16][OWP]
  float* gl = (float*)(smem + 128*KP*2 + 16*OWP*2);         // [64][33] gates
  float* la = gl + 64*33;                                   // [4][16][17] loss partials

  const int tid = threadIdx.x;
  const int gid = blockIdx.x & 31;
  const int q   = blockIdx.x >> 5;
  const int b_base = gid << 4;
  const int j_base = q << 5;

  // load W slice: LDS row r (r>>5 = gate, r&31 = jj) <-> zcol = gate*256 + j_base + jj
  for (int i = tid; i < 128*128; i += 256){
    int r = i >> 7, c4 = (i & 127) << 2;
    int zc = ((r >> 5) << 8) + j_base + (r & 31);
    *(uint2*)(Wl + r*KP + c4) = *(const uint2*)(Wt + zc*512 + c4);
  }
  // out_W slice: 16 out-cols [q*16 .. q*16+16)
  for (int i = tid; i < 16*64; i += 256){
    int r = i >> 6, c4 = (i & 63) << 2;
    *(uint2*)(oWl + r*OWP + c4) = *(const uint2*)(oWh + (q*16 + r)*256 + c4);
  }
  __syncthreads();

  const int wv = tid >> 6;        // wave = gate (0:i 1:f 2:g 3:o)
  const int lane = tid & 63;
  const int lrow = lane & 15;
  const int lq = lane >> 4;
  const int arow = b_base + lrow; // A-fragment row (batch)

  const float bias0 = bih[(wv<<8) + j_base + lrow]      + bhh[(wv<<8) + j_base + lrow];
  const float bias1 = bih[(wv<<8) + j_base + 16 + lrow] + bhh[(wv<<8) + j_base + 16 + lrow];

  // loss-element mapping for the cell phase: (row=tid>>4, col=tid&15)
  const int l_r = tid >> 4, l_c = tid & 15;
  const float ob2 = outb[(q<<4) + l_c];

  float c0 = 0.f, c1 = 0.f;     // cell state, register-resident all 127 steps
  float lossAcc = 0.f;

  const f16* wb0 = Wl + ((wv<<5) + lrow)*KP + (lq<<3);
  const f16* wb1 = wb0 + 16*KP;

  // poll line: lane tid&7 watches producer q'=(tid&7) of this group
  unsigned int* myflag = flags + ((gid<<3) + (tid&7))*FLAG_STRIDE;
  unsigned int* ourflag = flags + ((gid<<3) + q)*FLAG_STRIDE;

  // ---- pipeline registers ----
  half8 xr[8], xn[8], gr[8], gn[8];
  float vpre = 0.f, mpre = 0.f, vnx = 0.f, mnx = 0.f;
  {
    const f16* xp = x_all + ((size_t)arow << 8) + (lq << 3);   // t=0
#pragma unroll
    for (int kk = 0; kk < 8; ++kk) xr[kk] = *(const half8*)(xp + (kk<<5));
#pragma unroll
    for (int kk = 0; kk < 8; ++kk) gr[kk] = xr[kk];  // dummy init (unused at t=0)
  }

  for (int t = 0; t < NSTEP; ++t){
    f32x4 acc0 = {0.f,0.f,0.f,0.f}, acc1 = {0.f,0.f,0.f,0.f}, accL = {0.f,0.f,0.f,0.f};

    // x half (K = 0..255) — uses registers prefetched last step; before poll.
#pragma unroll
    for (int kk = 0; kk < 8; ++kk){
      half8 b0 = *(const half8*)(wb0 + (kk<<5));
      half8 b1 = *(const half8*)(wb1 + (kk<<5));
      acc0 = __builtin_amdgcn_mfma_f32_16x16x32_f16(xr[kk], b0, acc0, 0,0,0);
      acc1 = __builtin_amdgcn_mfma_f32_16x16x32_f16(xr[kk], b1, acc1, 0,0,0);
    }

    const int tn = (t < NSTEP-1) ? t+1 : t;   // prefetch target
    const f16* xpn = x_all + (((size_t)tn*B_ + arow) << 8) + (lq << 3);
    const f16* gpn = g_all + (((size_t)tn*B_ + arow) << 8) + (lq << 3);
    const size_t on = ((size_t)(b_base + l_r) << 14) + (tn << 7) + (q<<4) + l_c;

    if (t > 0){
      // wait for all 8 producers of this group to have published h(t)
      {
        int guard = 0;
        while (__hip_atomic_load(myflag, __ATOMIC_RELAXED,
                                 __HIP_MEMORY_SCOPE_AGENT) < (unsigned)t
               && guard < 4000000){
          ++guard;
          __builtin_amdgcn_s_sleep(1);
        }
        __builtin_amdgcn_fence(__ATOMIC_ACQUIRE, "agent");  // per-wave L1 inv
      }

      // h loads first (L2-hit), then next-step prefetches (HBM, off-chain)
      const f16* hp = h_buf + ((((t&1)*B_) + arow) << 8) + (lq << 3);
      half8 hr[8];
#pragma unroll
      for (int kk = 0; kk < 8; ++kk) hr[kk] = *(const half8*)(hp + (kk<<5));
#pragma unroll
      for (int kk = 0; kk < 8; ++kk) xn[kk] = *(const half8*)(xpn + (kk<<5));
#pragma unroll
      for (int kk = 0; kk < 8; ++kk) gn[kk] = *(const half8*)(gpn + (kk<<5));
      vnx = values[on]; mnx = masks[on];

      // h half (K = 256..511): A = h_t * gamma_t ; raw h feeds loss (K-split)
#pragma unroll
      for (int kk = 0; kk < 8; ++kk){
        half8 hrv = hr[kk];
        if ((kk >> 1) == wv){
          half8 bo = *(const half8*)(oWl + lrow*OWP + (kk<<5) + (lq<<3));
          accL = __builtin_amdgcn_mfma_f32_16x16x32_f16(hrv, bo, accL, 0,0,0);
        }
        half8 hg = hrv * gr[kk];
        half8 b0 = *(const half8*)(wb0 + 256 + (kk<<5));
        half8 b1 = *(const half8*)(wb1 + 256 + (kk<<5));
        acc0 = __builtin_amdgcn_mfma_f32_16x16x32_f16(hg, b0, acc0, 0,0,0);
        acc1 = __builtin_amdgcn_mfma_f32_16x16x32_f16(hg, b1, acc1, 0,0,0);
      }
      // publish loss partials (C layout: row=lq*4+r, col=lrow)
#pragma unroll
      for (int r = 0; r < 4; ++r)
        la[wv*272 + ((lq<<2)+r)*17 + lrow] = accL[r];
    } else {
      // t==0: no h half; just prefetch for t=1
#pragma unroll
      for (int kk = 0; kk < 8; ++kk) xn[kk] = *(const half8*)(xpn + (kk<<5));
#pragma unroll
      for (int kk = 0; kk < 8; ++kk) gn[kk] = *(const half8*)(gpn + (kk<<5));
      vnx = values[on]; mnx = masks[on];
    }

    // publish gates to LDS (C layout: row=(lane>>4)*4+r, col=lane&15)
#pragma unroll
    for (int r = 0; r < 4; ++r){
      int row = (lq<<2) + r;
      gl[((wv<<4) + row)*33 + lrow]      = acc0[r] + bias0;
      gl[((wv<<4) + row)*33 + 16 + lrow] = acc1[r] + bias1;
    }
    __syncthreads();

    // loss term t-1 (output of step t-1 vs values[:,t,:])
    if (t > 0){
      float s = la[l_r*17 + l_c] + la[272 + l_r*17 + l_c]
              + la[544 + l_r*17 + l_c] + la[816 + l_r*17 + l_c];
      lossAcc += fabsf(vpre - (s + ob2)) * mpre * dinv[t];
    }

    // cell update: 512 elems [16 rows x 32 cols], 2 per thread
#pragma unroll
    for (int pp = 0; pp < 2; ++pp){
      int e = tid + (pp<<8);
      int row = e >> 5, col = e & 31;
      float zi = gl[row*33 + col];
      float zf = gl[(16+row)*33 + col];
      float zg = gl[(32+row)*33 + col];
      float zo = gl[(48+row)*33 + col];
      float cp = pp ? c1 : c0;
      float cn = sigm(zf)*cp + sigm(zi)*tanh_(zg);
      float hn = sigm(zo)*tanh_(cn);
      if (pp) c1 = cn; else c0 = cn;
      int b = b_base + row, j = j_base + col;
      if (t < NSTEP-1){
        h_buf[((((t+1)&1)*B_ + b) << 8) + j] = (f16)hn;
      } else {
        d_out[(b<<8) + j] = hn;               // h, fp32 from registers
        d_out[(1<<17) + (b<<8) + j] = cn;     // c
      }
    }

    if (t < NSTEP-1){
      // __syncthreads drains vmcnt(0) for every wave -> all h stores of this
      // WG are in (same-XCD) L2 before tid0's monotone flag store issues.
      __syncthreads();
      if (tid == 0)
        __hip_atomic_store(ourflag, (unsigned)(t+1),
                           __ATOMIC_RELAXED, __HIP_MEMORY_SCOPE_AGENT);
    }

    // rotate pipeline registers
#pragma unroll
    for (int kk = 0; kk < 8; ++kk){ xr[kk] = xn[kk]; gr[kk] = gn[kk]; }
    vpre = vnx; mpre = mnx;
  }

  // block-wide loss reduction (all threads hold partials now)
  __syncthreads();
  gl[tid] = lossAcc;
  __syncthreads();
  for (int off = 128; off > 0; off >>= 1){
    if (tid < off) gl[tid] += gl[tid + off];
    __syncthreads();
  }
  if (tid == 0) atomicAdd(loss_accum, gl[0]);
}

// ---------------------------------------------------------------------------
__global__ __launch_bounds__(256) void kepi(
    const float* __restrict__ h_out, const float* __restrict__ outW,
    const float* __restrict__ outb, const float* __restrict__ values,
    const float* __restrict__ masks, float* __restrict__ num_final)
{
  int idx = blockIdx.x*256 + threadIdx.x;   // 65536 = 512*128
  int b = idx >> 7, f = idx & 127;
  const float* hr = h_out + (b << 8);
  const float* wr = outW + (f << 8);
  float s0 = 0.f, s1 = 0.f, s2 = 0.f, s3 = 0.f;
  for (int j = 0; j < 256; j += 4){
    s0 += hr[j]   * wr[j];
    s1 += hr[j+1] * wr[j+1];
    s2 += hr[j+2] * wr[j+2];
    s3 += hr[j+3] * wr[j+3];
  }
  float s = s0 + s1 + s2 + s3 + outb[f];
  size_t o = ((size_t)b << 14) + (127 << 7) + f;
  float term = fabsf(values[o] - s) * masks[o];
  __shared__ float red[256];
  red[threadIdx.x] = term; __syncthreads();
  for (int off = 128; off > 0; off >>= 1){
    if (threadIdx.x < off) red[threadIdx.x] += red[threadIdx.x + off];
    __syncthreads();
  }
  if (threadIdx.x == 0) atomicAdd(num_final, red[0]);
}

__global__ void kfin(const float* __restrict__ loss_accum,
                     const float* __restrict__ num_final,
                     const float* __restrict__ dinv, float* __restrict__ d_out)
{
  d_out[1<<18] = loss_accum[0] + num_final[0] * dinv[127];
}

// ---------------------------------------------------------------------------
extern "C" void kernel_launch(void* const* d_in, const int* in_sizes, int n_in,
                              void* d_out, int out_size, void* d_ws, size_t ws_size,
                              hipStream_t stream)
{
  const float* values = (const float*)d_in[0];
  const float* masks  = (const float*)d_in[1];
  const float* deltas = (const float*)d_in[2];
  const float* featW  = (const float*)d_in[3];
  const float* featb  = (const float*)d_in[4];
  const float* tempW  = (const float*)d_in[5];
  const float* tempb  = (const float*)d_in[6];
  const float* decW   = (const float*)d_in[7];
  const float* decb   = (const float*)d_in[8];
  const float* Wih    = (const float*)d_in[9];
  const float* Whh    = (const float*)d_in[10];
  const float* bih    = (const float*)d_in[11];
  const float* bhh    = (const float*)d_in[12];
  const float* outW   = (const float*)d_in[13];
  const float* outb   = (const float*)d_in[14];
  float* out = (float*)d_out;
  char* ws = (char*)d_ws;

  f16* Wt    = (f16*)(ws + 0);                 // 1 MB
  f16* oWh   = (f16*)(ws + 1048576);           // 64 KB
  float* fWT = (float*)(ws + 1114112);         // 64 KB
  float* tWm = (float*)(ws + 1179648);         // 64 KB
  float* dWT = (float*)(ws + 1245184);         // 128 KB
  float* dinv = (float*)(ws + 1376256);        // 512 B
  unsigned int* flags = (unsigned int*)(ws + 1376768);  // 16 KB padded lines
  float* accums = (float*)(ws + 1393152);      // [0]=loss_accum [1]=num_final
  f16* h_buf = (f16*)(ws + 1393664);           // 512 KB ping-pong
  f16* x_all = (f16*)(ws + 1917952);           // 32 MB
  f16* g_all = (f16*)(ws + 35472384);          // 32 MB  (end ~69 MB)

  kprep<<<256, 256, 0, stream>>>(Wih, Whh, outW, featW, tempW, decW,
                                 Wt, oWh, fWT, tWm, dWT, flags, accums);
  kdenom<<<128, 256, 0, stream>>>(masks, dinv);
  k1<<<512, 256, 0, stream>>>(values, masks, fWT, tWm, featb, tempb, x_all);
  k2<<<512, 256, 0, stream>>>(deltas, dWT, decb, g_all);

  const int SLDS = 128*KP*2 + 16*OWP*2 + 64*33*4 + 4*16*17*4;   // 154368 B
  hipFuncSetAttribute((const void*)kscan, hipFuncAttributeMaxDynamicSharedMemorySize, SLDS);
  kscan<<<256, 256, SLDS, stream>>>(x_all, g_all, Wt, oWh, bih, bhh, outb,
                                    values, masks, dinv, h_buf, flags,
                                    accums, out);

  kepi<<<256, 256, 0, stream>>>(out, outW, outb, values, masks, accums + 1);
  kfin<<<1, 1, 0, stream>>>(accums, accums + 1, dinv, out);
}

// Round 4
// 1320.368 us; speedup vs baseline: 1.3008x; 1.3008x over previous
//
#include <hip/hip_runtime.h>

// ---------------------------------------------------------------------------
// Encoder: feature/temporal regression + temporal-decay LSTM scan + L1 loss
// B=512 T=128 F=128 H=256.  Outputs: h[512,256], c[512,256], loss (fp32).
//
// R3 -> R4: revert to the R2 skeleton (it was faster: 900 vs 1150 us) and
// apply exactly two surgical changes, keeping all loads retired before any
// barrier (R3's lesson: __syncthreads drains vmcnt(0), so cross-barrier
// in-flight prefetches stall the barrier and regress):
//  1. Monotone per-producer flag lines: producer q of group gid stores (t+1)
//     to its own 64B line (no 8-way same-line fetch_add serialization at the
//     coherence point). Wave 0 polls all 8 lines via lanes 0..7, one acquire
//     fence on success (CU-wide L1 inv), __syncthreads broadcast (as in R2).
//  2. All h-independent work hoisted BEFORE the poll: x/g/loss-v/m loads and
//     the full x-half MFMA run while waiting for producers; they are consumed
//     (hence retired) before the fence/barriers, so nothing is left in flight.
// ---------------------------------------------------------------------------

typedef _Float16 f16;
typedef _Float16 half8 __attribute__((ext_vector_type(8)));
typedef float f32x4 __attribute__((ext_vector_type(4)));

#define B_ 512
#define T_ 128
#define F_ 128
#define H_ 256
#define NSTEP 127
#define KP 520     // padded LDS row stride (elems) for W slice
#define OWP 264    // padded LDS row stride for out_W slice
#define FLAG_STRIDE 16   // dwords: one 64B line per producer WG

__device__ __forceinline__ float sigm(float x){ return 1.f/(1.f + __expf(-x)); }
__device__ __forceinline__ float tanh_(float x){
  float e = __expf(-2.f*fabsf(x));
  float t = (1.f - e)/(1.f + e);
  return x >= 0.f ? t : -t;
}

// ---------------------------------------------------------------------------
__global__ void kprep(const float* __restrict__ Wih, const float* __restrict__ Whh,
                      const float* __restrict__ outW,
                      const float* __restrict__ featW, const float* __restrict__ tempW,
                      const float* __restrict__ decW,
                      f16* __restrict__ Wt, f16* __restrict__ oWh,
                      float* __restrict__ fWT, float* __restrict__ tWm,
                      float* __restrict__ dWT, unsigned int* __restrict__ flags,
                      float* __restrict__ accums)
{
  int idx = blockIdx.x*256 + threadIdx.x;
  int stride = gridDim.x*256;
  // W_cat[zc][k]: k<256 -> W_ih[zc][k] (inp = [values_hat, masks]); k>=256 -> W_hh
  for (int i = idx; i < 1024*512; i += stride){
    int zc = i >> 9, k = i & 511;
    float w = (k < 256) ? Wih[zc*256 + k] : Whh[zc*256 + k - 256];
    Wt[i] = (f16)w;
  }
  for (int i = idx; i < 128*256; i += stride) oWh[i] = (f16)outW[i];
  // fWT[g][f] = feat_W[f][g] with diag zeroed (einsum 'btf,gf->btg' masked)
  for (int i = idx; i < 128*128; i += stride){
    int g = i >> 7, f = i & 127;
    fWT[i] = (f == g) ? 0.f : featW[f*128 + g];
  }
  for (int i = idx; i < 128*128; i += stride){
    int t = i >> 7, s = i & 127;
    tWm[i] = (s == t) ? 0.f : tempW[i];
  }
  // dWT[f][h] = decay_W[h][f]
  for (int i = idx; i < 128*256; i += stride){
    int f = i >> 8, h = i & 255;
    dWT[i] = decW[h*128 + f];
  }
  for (int i = idx; i < 256*FLAG_STRIDE; i += stride) flags[i] = 0u;
  if (idx < 2) accums[idx] = 0.f;
}

// ---------------------------------------------------------------------------
__global__ __launch_bounds__(256) void kdenom(const float* __restrict__ masks,
                                              float* __restrict__ dinv)
{
  int t = blockIdx.x;
  __shared__ float red[256];
  float s = 0.f;
  for (int i = threadIdx.x; i < B_*F_; i += 256){
    int b = i >> 7, f = i & 127;
    s += masks[((size_t)b << 14) + (t << 7) + f];
  }
  red[threadIdx.x] = s; __syncthreads();
  for (int o = 128; o > 0; o >>= 1){
    if (threadIdx.x < o) red[threadIdx.x] += red[threadIdx.x + o];
    __syncthreads();
  }
  if (threadIdx.x == 0) dinv[t] = 1.f/(red[0] + 1e-5f);
}

// ---------------------------------------------------------------------------
// values_hat: vhat[b,t,f] = sum_g v[b,t,g]*fWT[g][f] + sum_s v[b,s,f]*tWm[t][s]
//                           + feat_b[f] + temp_b[t]
// x = v*m + vhat*(1-m); x_all[t][b][0:128]=x, [128:256]=m
__global__ __launch_bounds__(256) void k1(
    const float* __restrict__ values, const float* __restrict__ masks,
    const float* __restrict__ fWT, const float* __restrict__ tWm,
    const float* __restrict__ featb, const float* __restrict__ tempb,
    f16* __restrict__ x_all)
{
  __shared__ float vbuf[128][128];   // 64 KB, 2 blocks/CU
  const int b = blockIdx.x, tid = threadIdx.x;
  const float* vb = values + ((size_t)b << 14);
  for (int i = tid; i < 128*128; i += 256) (&vbuf[0][0])[i] = vb[i];
  __syncthreads();
  const int f = tid & 127, th = tid >> 7;
  const float fb = featb[f];
  for (int tt = 0; tt < 4; ++tt){
    const int t0 = th*64 + tt*16;
    float acc[16];
#pragma unroll
    for (int i = 0; i < 16; ++i) acc[i] = 0.f;
    for (int g = 0; g < 128; ++g){
      float w = fWT[(g<<7) + f];
#pragma unroll
      for (int i = 0; i < 16; ++i) acc[i] += vbuf[t0+i][g] * w;
    }
    for (int s = 0; s < 128; ++s){
      float v = vbuf[s][f];
#pragma unroll
      for (int i = 0; i < 16; ++i) acc[i] += v * tWm[((t0+i)<<7) + s];
    }
#pragma unroll
    for (int i = 0; i < 16; ++i){
      int t = t0 + i;
      float vh = acc[i] + fb + tempb[t];
      float m = masks[((size_t)b << 14) + (t << 7) + f];
      float v = vbuf[t][f];
      float x = v*m + vh*(1.f - m);
      size_t o = (((size_t)t << 9) + b) << 8;
      x_all[o + f] = (f16)x;
      x_all[o + 128 + f] = (f16)m;
    }
  }
}

// ---------------------------------------------------------------------------
__global__ __launch_bounds__(256) void k2(
    const float* __restrict__ deltas, const float* __restrict__ dWT,
    const float* __restrict__ decb, f16* __restrict__ g_all)
{
  __shared__ float dbuf[128][128];
  const int b = blockIdx.x, tid = threadIdx.x;
  const float* dp = deltas + ((size_t)b << 14);
  for (int i = tid; i < 128*128; i += 256) (&dbuf[0][0])[i] = dp[i];
  __syncthreads();
  const float bias = decb[tid];
  for (int tt = 0; tt < 8; ++tt){
    float acc[16];
#pragma unroll
    for (int i = 0; i < 16; ++i) acc[i] = 0.f;
    for (int fch = 0; fch < 128; ++fch){
      float w = dWT[(fch<<8) + tid];
#pragma unroll
      for (int i = 0; i < 16; ++i) acc[i] += dbuf[tt*16+i][fch] * w;
    }
#pragma unroll
    for (int i = 0; i < 16; ++i){
      int t = tt*16 + i;
      float gv = __expf(-fabsf(acc[i] + bias));
      g_all[((((size_t)t << 9) + b) << 8) + tid] = (f16)gv;
    }
  }
}

// ---------------------------------------------------------------------------
// Persistent scan. grid=256: gid=blockIdx&31 (row tile, 16 rows), q=blockIdx>>5
// (col chunk, 32 h-cols => 128 z-cols across 4 gates). 1 WG/CU (LDS-forced).
// Group {gid, gid+32, ..., gid+224} lands on one XCD under round-robin
// blockIdx->XCD mapping (all ≡ gid mod 8) -> same-XCD L2 is the coherence
// point for h_buf; one acquire fence (CU-wide L1 inv) per step by wave 0.
__global__ __launch_bounds__(256, 1) void kscan(
    const f16* __restrict__ x_all, const f16* __restrict__ g_all,
    const f16* __restrict__ Wt, const f16* __restrict__ oWh,
    const float* __restrict__ bih, const float* __restrict__ bhh,
    const float* __restrict__ outb,
    const float* __restrict__ values, const float* __restrict__ masks,
    const float* __restrict__ dinv,
    f16* __restrict__ h_buf, unsigned int* __restrict__ flags,
    float* __restrict__ loss_accum, float* __restrict__ d_out)
{
  extern __shared__ char smem[];
  f16* Wl  = (f16*)smem;                                // [128][KP]
  f16* oWl = (f16*)(smem + 128*KP*2);                   // [16][OWP]
  float* gl = (float*)(smem + 128*KP*2 + 16*OWP*2);     // [64][33] gate exchange

  const int tid = threadIdx.x;
  const int gid = blockIdx.x & 31;
  const int q   = blockIdx.x >> 5;
  const int b_base = gid << 4;
  const int j_base = q << 5;

  // load W slice: LDS row r (r>>5 = gate, r&31 = jj) <-> zcol = gate*256 + j_base + jj
  for (int i = tid; i < 128*128; i += 256){
    int r = i >> 7, c4 = (i & 127) << 2;
    int zc = ((r >> 5) << 8) + j_base + (r & 31);
    *(uint2*)(Wl + r*KP + c4) = *(const uint2*)(Wt + zc*512 + c4);
  }
  // out_W slice: 16 out-cols [q*16 .. q*16+16)
  for (int i = tid; i < 16*64; i += 256){
    int r = i >> 6, c4 = (i & 63) << 2;
    *(uint2*)(oWl + r*OWP + c4) = *(const uint2*)(oWh + (q*16 + r)*256 + c4);
  }
  __syncthreads();

  const int wv = tid >> 6;        // wave = gate (0:i 1:f 2:g 3:o)
  const int lane = tid & 63;
  const int lrow = lane & 15;
  const int lq = lane >> 4;
  const int arow = b_base + lrow; // A-fragment row (batch)

  const float bias0 = bih[(wv<<8) + j_base + lrow]      + bhh[(wv<<8) + j_base + lrow];
  const float bias1 = bih[(wv<<8) + j_base + 16 + lrow] + bhh[(wv<<8) + j_base + 16 + lrow];
  const float ob = outb[(q<<4) + lrow];

  float c0 = 0.f, c1 = 0.f;     // cell state, register-resident all 127 steps
  float lossAcc = 0.f;

  const f16* wb0 = Wl + ((wv<<5) + lrow)*KP + (lq<<3);
  const f16* wb1 = wb0 + 16*KP;

  // flag lines: producer q' of group gid owns flags[(gid*8+q')*FLAG_STRIDE].
  // wave 0 lanes 0..7 poll the 8 producers (other lanes alias line 0..7 too;
  // same-address lanes broadcast).
  unsigned int* pollflag = flags + ((gid<<3) + (lane & 7))*FLAG_STRIDE;
  unsigned int* ourflag  = flags + ((gid<<3) + q)*FLAG_STRIDE;

  for (int t = 0; t < NSTEP; ++t){
    f32x4 acc0 = {0.f,0.f,0.f,0.f}, acc1 = {0.f,0.f,0.f,0.f}, accL = {0.f,0.f,0.f,0.f};

    // ---- h-independent phase (runs while producers finish h(t)) ----
    // x fragment + gamma fragment + loss v/m for this step: none depend on h.
    const f16* xp = x_all + (((size_t)t*B_ + arow) << 8) + (lq << 3);
    const f16* gp = g_all + (((size_t)t*B_ + arow) << 8) + (lq << 3);
    half8 xr[8], gr[8];
#pragma unroll
    for (int kk = 0; kk < 8; ++kk) xr[kk] = *(const half8*)(xp + (kk<<5));
#pragma unroll
    for (int kk = 0; kk < 8; ++kk) gr[kk] = *(const half8*)(gp + (kk<<5));

    float vv[4], mm[4], dinvt = 0.f;
    if (wv == 0 && t > 0){
      dinvt = dinv[t];
#pragma unroll
      for (int r = 0; r < 4; ++r){
        size_t o = ((size_t)(b_base + (lq<<2) + r) << 14) + (t << 7) + (q<<4) + lrow;
        vv[r] = values[o]; mm[r] = masks[o];
      }
    }

    // x half (K = 0..255): consumed (and thus retired) before the poll/fence.
#pragma unroll
    for (int kk = 0; kk < 8; ++kk){
      half8 b0 = *(const half8*)(wb0 + (kk<<5));
      half8 b1 = *(const half8*)(wb1 + (kk<<5));
      acc0 = __builtin_amdgcn_mfma_f32_16x16x32_f16(xr[kk], b0, acc0, 0,0,0);
      acc1 = __builtin_amdgcn_mfma_f32_16x16x32_f16(xr[kk], b1, acc1, 0,0,0);
    }

    if (t > 0){
      // ---- wait for all 8 producers to publish h(t) ----
      if (wv == 0){
        int guard = 0;
        while (__hip_atomic_load(pollflag, __ATOMIC_RELAXED,
                                 __HIP_MEMORY_SCOPE_AGENT) < (unsigned)t
               && guard < 4000000){
          ++guard;
          __builtin_amdgcn_s_sleep(1);
        }
        // one CU-wide L1 invalidate; orders h_buf loads after the flags
        __builtin_amdgcn_fence(__ATOMIC_ACQUIRE, "agent");
      }
      __syncthreads();

      // h half (K = 256..511): A = h_t * gamma_t ; raw h feeds loss term t-1
      const f16* hp = h_buf + ((((t&1)*B_) + arow) << 8) + (lq << 3);
#pragma unroll
      for (int kk = 0; kk < 8; ++kk){
        half8 hr = *(const half8*)(hp + (kk<<5));
        if (wv == 0){
          half8 bo = *(const half8*)(oWl + lrow*OWP + (kk<<5) + (lq<<3));
          accL = __builtin_amdgcn_mfma_f32_16x16x32_f16(hr, bo, accL, 0,0,0);
        }
        half8 hg = hr * gr[kk];
        half8 b0 = *(const half8*)(wb0 + 256 + (kk<<5));
        half8 b1 = *(const half8*)(wb1 + 256 + (kk<<5));
        acc0 = __builtin_amdgcn_mfma_f32_16x16x32_f16(hg, b0, acc0, 0,0,0);
        acc1 = __builtin_amdgcn_mfma_f32_16x16x32_f16(hg, b1, acc1, 0,0,0);
      }
      if (wv == 0){
#pragma unroll
        for (int r = 0; r < 4; ++r){
          float ov = accL[r] + ob;
          lossAcc += fabsf(vv[r] - ov) * mm[r] * dinvt;
        }
      }
    }

    // publish gates to LDS (C layout: row=(lane>>4)*4+r, col=lane&15)
#pragma unroll
    for (int r = 0; r < 4; ++r){
      int row = (lq<<2) + r;
      gl[((wv<<4) + row)*33 + lrow]      = acc0[r] + bias0;
      gl[((wv<<4) + row)*33 + 16 + lrow] = acc1[r] + bias1;
    }
    __syncthreads();

    // cell update: 512 elems [16 rows x 32 cols], 2 per thread
#pragma unroll
    for (int pp = 0; pp < 2; ++pp){
      int e = tid + (pp<<8);
      int row = e >> 5, col = e & 31;
      float zi = gl[row*33 + col];
      float zf = gl[(16+row)*33 + col];
      float zg = gl[(32+row)*33 + col];
      float zo = gl[(48+row)*33 + col];
      float cp = pp ? c1 : c0;
      float cn = sigm(zf)*cp + sigm(zi)*tanh_(zg);
      float hn = sigm(zo)*tanh_(cn);
      if (pp) c1 = cn; else c0 = cn;
      int b = b_base + row, j = j_base + col;
      if (t < NSTEP-1){
        h_buf[((((t+1)&1)*B_ + b) << 8) + j] = (f16)hn;
      } else {
        d_out[(b<<8) + j] = hn;               // h, fp32 from registers
        d_out[(1<<17) + (b<<8) + j] = cn;     // c
      }
    }

    if (t < NSTEP-1){
      // __syncthreads drains vmcnt(0) for every wave -> all h stores of this
      // WG are visible before tid0's monotone flag store issues. Only h
      // stores are outstanding here (all loads were consumed pre-barrier).
      __syncthreads();
      if (tid == 0)
        __hip_atomic_store(ourflag, (unsigned)(t+1),
                           __ATOMIC_RELAXED, __HIP_MEMORY_SCOPE_AGENT);
    }
  }

  // loss terms 0..125 reduction (wave 0 holds them)
  if (wv == 0){
#pragma unroll
    for (int off = 32; off > 0; off >>= 1)
      lossAcc += __shfl_down(lossAcc, off, 64);
    if (lane == 0) atomicAdd(loss_accum, lossAcc);
  }
}

// ---------------------------------------------------------------------------
__global__ __launch_bounds__(256) void kepi(
    const float* __restrict__ h_out, const float* __restrict__ outW,
    const float* __restrict__ outb, const float* __restrict__ values,
    const float* __restrict__ masks, float* __restrict__ num_final)
{
  int idx = blockIdx.x*256 + threadIdx.x;   // 65536 = 512*128
  int b = idx >> 7, f = idx & 127;
  const float* hr = h_out + (b << 8);
  const float* wr = outW + (f << 8);
  float s0 = 0.f, s1 = 0.f, s2 = 0.f, s3 = 0.f;
  for (int j = 0; j < 256; j += 4){
    s0 += hr[j]   * wr[j];
    s1 += hr[j+1] * wr[j+1];
    s2 += hr[j+2] * wr[j+2];
    s3 += hr[j+3] * wr[j+3];
  }
  float s = s0 + s1 + s2 + s3 + outb[f];
  size_t o = ((size_t)b << 14) + (127 << 7) + f;
  float term = fabsf(values[o] - s) * masks[o];
  __shared__ float red[256];
  red[threadIdx.x] = term; __syncthreads();
  for (int off = 128; off > 0; off >>= 1){
    if (threadIdx.x < off) red[threadIdx.x] += red[threadIdx.x + off];
    __syncthreads();
  }
  if (threadIdx.x == 0) atomicAdd(num_final, red[0]);
}

__global__ void kfin(const float* __restrict__ loss_accum,
                     const float* __restrict__ num_final,
                     const float* __restrict__ dinv, float* __restrict__ d_out)
{
  d_out[1<<18] = loss_accum[0] + num_final[0] * dinv[127];
}

// ---------------------------------------------------------------------------
extern "C" void kernel_launch(void* const* d_in, const int* in_sizes, int n_in,
                              void* d_out, int out_size, void* d_ws, size_t ws_size,
                              hipStream_t stream)
{
  const float* values = (const float*)d_in[0];
  const float* masks  = (const float*)d_in[1];
  const float* deltas = (const float*)d_in[2];
  const float* featW  = (const float*)d_in[3];
  const float* featb  = (const float*)d_in[4];
  const float* tempW  = (const float*)d_in[5];
  const float* tempb  = (const float*)d_in[6];
  const float* decW   = (const float*)d_in[7];
  const float* decb   = (const float*)d_in[8];
  const float* Wih    = (const float*)d_in[9];
  const float* Whh    = (const float*)d_in[10];
  const float* bih    = (const float*)d_in[11];
  const float* bhh    = (const float*)d_in[12];
  const float* outW   = (const float*)d_in[13];
  const float* outb   = (const float*)d_in[14];
  float* out = (float*)d_out;
  char* ws = (char*)d_ws;

  f16* Wt    = (f16*)(ws + 0);                 // 1 MB
  f16* oWh   = (f16*)(ws + 1048576);           // 64 KB
  float* fWT = (float*)(ws + 1114112);         // 64 KB
  float* tWm = (float*)(ws + 1179648);         // 64 KB
  float* dWT = (float*)(ws + 1245184);         // 128 KB
  float* dinv = (float*)(ws + 1376256);        // 512 B
  unsigned int* flags = (unsigned int*)(ws + 1376768);  // 16 KB padded lines
  float* accums = (float*)(ws + 1393152);      // [0]=loss_accum [1]=num_final
  f16* h_buf = (f16*)(ws + 1393664);           // 512 KB ping-pong
  f16* x_all = (f16*)(ws + 1917952);           // 32 MB
  f16* g_all = (f16*)(ws + 35472384);          // 32 MB  (end ~69 MB)

  kprep<<<256, 256, 0, stream>>>(Wih, Whh, outW, featW, tempW, decW,
                                 Wt, oWh, fWT, tWm, dWT, flags, accums);
  kdenom<<<128, 256, 0, stream>>>(masks, dinv);
  k1<<<512, 256, 0, stream>>>(values, masks, fWT, tWm, featb, tempb, x_all);
  k2<<<512, 256, 0, stream>>>(deltas, dWT, decb, g_all);

  const int SLDS = 128*KP*2 + 16*OWP*2 + 64*33*4;   // 150016 B
  hipFuncSetAttribute((const void*)kscan, hipFuncAttributeMaxDynamicSharedMemorySize, SLDS);
  kscan<<<256, 256, SLDS, stream>>>(x_all, g_all, Wt, oWh, bih, bhh, outb,
                                    values, masks, dinv, h_buf, flags,
                                    accums, out);

  kepi<<<256, 256, 0, stream>>>(out, outW, outb, values, masks, accums + 1);
  kfin<<<1, 1, 0, stream>>>(accums, accums + 1, dinv, out);
}

// Round 5
// 1104.765 us; speedup vs baseline: 1.5547x; 1.1952x over previous
//
#include <hip/hip_runtime.h>

// ---------------------------------------------------------------------------
// Encoder: feature/temporal regression + temporal-decay LSTM scan + L1 loss
// B=512 T=128 F=128 H=256.  Outputs: h[512,256], c[512,256], loss (fp32).
//
// R4 -> R5:
//  1. kscan flags: agent-scope atomics (sc1 -> LLC round trip ~600cyc each)
//     replaced by plain volatile loads/stores (sc0 -> same-XCD L2 ~200cyc).
//     The h data already relies on same-XCD L2 coherence (group blockIdx ≡
//     gid mod 8 under round-robin XCD mapping; validated 4 rounds). One
//     acquire fence per step (wave0, CU L1 inv) kept for h coherence.
//  2. k1/k2 rewritten as f16 MFMA GEMMs (were scalar VALU/LDS-bound loops,
//     ~450 us combined). k1: C[t][f] = V·featW^T(masked) + tWm·V per batch,
//     V + V^T staged in LDS, weight B-frags streamed from L2 (f16, made by
//     kprep). k2: gamma GEMM same pattern. fp32 MFMA accumulate; f16 input
//     rounding is within the f16 x_all/g_all storage noise already present.
// ---------------------------------------------------------------------------

typedef _Float16 f16;
typedef _Float16 half8 __attribute__((ext_vector_type(8)));
typedef float f32x4 __attribute__((ext_vector_type(4)));

#define B_ 512
#define T_ 128
#define F_ 128
#define H_ 256
#define NSTEP 127
#define KP 520     // padded LDS row stride (elems) for W slice (kscan)
#define OWP 264    // padded LDS row stride for out_W slice (kscan)
#define PV 136     // LDS row stride f16 for V/Vt/D tiles (272B = 17*16 ✓ b128-aligned)
#define FLAG_STRIDE 16   // dwords: one 64B line per producer WG

__device__ __forceinline__ float sigm(float x){ return 1.f/(1.f + __expf(-x)); }
__device__ __forceinline__ float tanh_(float x){
  float e = __expf(-2.f*fabsf(x));
  float t = (1.f - e)/(1.f + e);
  return x >= 0.f ? t : -t;
}

// ---------------------------------------------------------------------------
__global__ void kprep(const float* __restrict__ Wih, const float* __restrict__ Whh,
                      const float* __restrict__ outW,
                      const float* __restrict__ featW, const float* __restrict__ tempW,
                      const float* __restrict__ decW,
                      f16* __restrict__ Wt, f16* __restrict__ oWh,
                      f16* __restrict__ fWh, f16* __restrict__ tWh,
                      f16* __restrict__ dWh, unsigned int* __restrict__ flags,
                      float* __restrict__ accums)
{
  int idx = blockIdx.x*256 + threadIdx.x;
  int stride = gridDim.x*256;
  // W_cat[zc][k]: k<256 -> W_ih[zc][k] (inp = [values_hat, masks]); k>=256 -> W_hh
  for (int i = idx; i < 1024*512; i += stride){
    int zc = i >> 9, k = i & 511;
    float w = (k < 256) ? Wih[zc*256 + k] : Whh[zc*256 + k - 256];
    Wt[i] = (f16)w;
  }
  for (int i = idx; i < 128*256; i += stride) oWh[i] = (f16)outW[i];
  // fWh[fo][gi] = feat_W[fo][gi], diag zeroed (B-frag layout: row=out col, contig k)
  for (int i = idx; i < 128*128; i += stride){
    int fo = i >> 7, gi = i & 127;
    fWh[i] = (fo == gi) ? (f16)0.f : (f16)featW[i];
  }
  // tWh[t][s] = temp_W[t][s], diag zeroed (A-frag layout: row=t, contig k=s)
  for (int i = idx; i < 128*128; i += stride){
    int t = i >> 7, s = i & 127;
    tWh[i] = (s == t) ? (f16)0.f : (f16)tempW[i];
  }
  // dWh[h][f] = decay_W[h][f] (B-frag layout)
  for (int i = idx; i < 256*128; i += stride) dWh[i] = (f16)decW[i];
  for (int i = idx; i < 256*FLAG_STRIDE; i += stride) flags[i] = 0u;
  if (idx < 2) accums[idx] = 0.f;
}

// ---------------------------------------------------------------------------
__global__ __launch_bounds__(256) void kdenom(const float* __restrict__ masks,
                                              float* __restrict__ dinv)
{
  int t = blockIdx.x;
  __shared__ float red[256];
  float s = 0.f;
  for (int i = threadIdx.x; i < B_*F_; i += 256){
    int b = i >> 7, f = i & 127;
    s += masks[((size_t)b << 14) + (t << 7) + f];
  }
  red[threadIdx.x] = s; __syncthreads();
  for (int o = 128; o > 0; o >>= 1){
    if (threadIdx.x < o) red[threadIdx.x] += red[threadIdx.x + o];
    __syncthreads();
  }
  if (threadIdx.x == 0) dinv[t] = 1.f/(red[0] + 1e-5f);
}

// ---------------------------------------------------------------------------
// k1 (MFMA): per batch b, C[t][f] = sum_g V[t][g]*featW[f][g](masked)
//                                  + sum_s tWm[t][s]*V[s][f]  + feat_b[f] + temp_b[t]
// x = (m!=0) ? v : C ; x_all[t][b][0:128]=x, [128:256]=m  (masks are exact 0/1)
__global__ __launch_bounds__(256) void k1(
    const float* __restrict__ values, const float* __restrict__ masks,
    const f16* __restrict__ fWh, const f16* __restrict__ tWh,
    const float* __restrict__ featb, const float* __restrict__ tempb,
    f16* __restrict__ x_all)
{
  extern __shared__ char sm1[];
  f16* V  = (f16*)sm1;                   // [128][PV]  row t, contig f
  f16* Vt = (f16*)(sm1 + 128*PV*2);      // [128][PV]  row f, contig t (transposed)
  const int b = blockIdx.x, tid = threadIdx.x;
  const float* vb = values + ((size_t)b << 14);

  // stage V and V^T (f16). thread owns (f, t-pair): coalesced global reads,
  // Vt write is one b32 (conflict ~8-way on 4f%32 pattern, staging only).
  for (int i = tid; i < 8192; i += 256){
    int f = i & 127, tp = i >> 7;      // tp = t/2
    float a = vb[(tp*2)*128 + f];
    float c = vb[(tp*2+1)*128 + f];
    f16 ha = (f16)a, hc = (f16)c;
    V[(tp*2)*PV + f]   = ha;
    V[(tp*2+1)*PV + f] = hc;
    union { f16 h[2]; unsigned u; } pk; pk.h[0] = ha; pk.h[1] = hc;
    *(unsigned*)(Vt + f*PV + tp*2) = pk.u;
  }
  __syncthreads();

  const int w = tid >> 6, lane = tid & 63, lrow = lane & 15, lq = lane >> 4;
  for (int ti2 = 0; ti2 < 2; ++ti2){
    const int t0 = (w*2 + ti2) << 4;
    half8 aV[4], aT[4];
#pragma unroll
    for (int kk = 0; kk < 4; ++kk){
      aV[kk] = *(const half8*)(V + (t0+lrow)*PV + kk*32 + lq*8);
      aT[kk] = *(const half8*)(tWh + (t0+lrow)*128 + kk*32 + lq*8);
    }
    float tb[4];
#pragma unroll
    for (int r = 0; r < 4; ++r) tb[r] = tempb[t0 + lq*4 + r];
#pragma unroll
    for (int fj = 0; fj < 8; ++fj){
      const int f0 = fj << 4;
      f32x4 acc = {0.f,0.f,0.f,0.f};
#pragma unroll
      for (int kk = 0; kk < 4; ++kk){
        half8 bF = *(const half8*)(fWh + (f0+lrow)*128 + kk*32 + lq*8);
        half8 bT = *(const half8*)(Vt  + (f0+lrow)*PV  + kk*32 + lq*8);
        acc = __builtin_amdgcn_mfma_f32_16x16x32_f16(aV[kk], bF, acc, 0,0,0);
        acc = __builtin_amdgcn_mfma_f32_16x16x32_f16(aT[kk], bT, acc, 0,0,0);
      }
      const float fb = featb[f0 + lrow];
#pragma unroll
      for (int r = 0; r < 4; ++r){
        int t = t0 + lq*4 + r, f = f0 + lrow;   // C layout: col=lane&15, row=quad*4+r
        float vh = acc[r] + fb + tb[r];
        float v = (float)V[t*PV + f];
        float m = masks[((size_t)b << 14) + t*128 + f];
        float x = (m != 0.0f) ? v : vh;
        size_t o = (((size_t)t*B_ + b) << 8);
        x_all[o + f]       = (f16)x;
        x_all[o + 128 + f] = (f16)m;
      }
    }
  }
}

// ---------------------------------------------------------------------------
// k2 (MFMA): gamma[t][h] = exp(-|sum_f D[t][f]*decW[h][f] + decb[h]|)
__global__ __launch_bounds__(256) void k2(
    const float* __restrict__ deltas, const f16* __restrict__ dWh,
    const float* __restrict__ decb, f16* __restrict__ g_all)
{
  __shared__ f16 D[128*PV];
  const int b = blockIdx.x, tid = threadIdx.x;
  const float* dp = deltas + ((size_t)b << 14);
  for (int i = tid; i < 8192; i += 256){
    int t = i >> 6, fd = (i & 63) << 1;
    float a = dp[t*128 + fd], c = dp[t*128 + fd + 1];
    union { f16 h[2]; unsigned u; } pk; pk.h[0] = (f16)a; pk.h[1] = (f16)c;
    *(unsigned*)(D + t*PV + fd) = pk.u;
  }
  __syncthreads();

  const int w = tid >> 6, lane = tid & 63, lrow = lane & 15, lq = lane >> 4;
  for (int ti2 = 0; ti2 < 2; ++ti2){
    const int t0 = (w*2 + ti2) << 4;
    half8 aD[4];
#pragma unroll
    for (int kk = 0; kk < 4; ++kk)
      aD[kk] = *(const half8*)(D + (t0+lrow)*PV + kk*32 + lq*8);
#pragma unroll
    for (int hj = 0; hj < 16; ++hj){
      const int h0 = hj << 4;
      f32x4 acc = {0.f,0.f,0.f,0.f};
#pragma unroll
      for (int kk = 0; kk < 4; ++kk){
        half8 bD = *(const half8*)(dWh + (h0+lrow)*128 + kk*32 + lq*8);
        acc = __builtin_amdgcn_mfma_f32_16x16x32_f16(aD[kk], bD, acc, 0,0,0);
      }
      const float db = decb[h0 + lrow];
#pragma unroll
      for (int r = 0; r < 4; ++r){
        int t = t0 + lq*4 + r, h = h0 + lrow;
        float gv = __expf(-fabsf(acc[r] + db));
        g_all[(((size_t)t*B_ + b) << 8) + h] = (f16)gv;
      }
    }
  }
}

// ---------------------------------------------------------------------------
// Persistent scan. grid=256: gid=blockIdx&31 (row tile, 16 rows), q=blockIdx>>5
// (col chunk, 32 h-cols => 128 z-cols across 4 gates). 1 WG/CU (LDS-forced).
// Group {gid, gid+32, ..., gid+224}: blockIdx ≡ gid (mod 8) -> one XCD under
// round-robin mapping -> same-XCD L2 is the coherence point for h_buf AND the
// flags (plain volatile ops, sc0: L1-bypass, L2-hit — no LLC round trips).
__global__ __launch_bounds__(256, 1) void kscan(
    const f16* __restrict__ x_all, const f16* __restrict__ g_all,
    const f16* __restrict__ Wt, const f16* __restrict__ oWh,
    const float* __restrict__ bih, const float* __restrict__ bhh,
    const float* __restrict__ outb,
    const float* __restrict__ values, const float* __restrict__ masks,
    const float* __restrict__ dinv,
    f16* __restrict__ h_buf, unsigned int* __restrict__ flags,
    float* __restrict__ loss_accum, float* __restrict__ d_out)
{
  extern __shared__ char smem[];
  f16* Wl  = (f16*)smem;                                // [128][KP]
  f16* oWl = (f16*)(smem + 128*KP*2);                   // [16][OWP]
  float* gl = (float*)(smem + 128*KP*2 + 16*OWP*2);     // [64][33] gate exchange

  const int tid = threadIdx.x;
  const int gid = blockIdx.x & 31;
  const int q   = blockIdx.x >> 5;
  const int b_base = gid << 4;
  const int j_base = q << 5;

  // load W slice: LDS row r (r>>5 = gate, r&31 = jj) <-> zcol = gate*256 + j_base + jj
  for (int i = tid; i < 128*128; i += 256){
    int r = i >> 7, c4 = (i & 127) << 2;
    int zc = ((r >> 5) << 8) + j_base + (r & 31);
    *(uint2*)(Wl + r*KP + c4) = *(const uint2*)(Wt + zc*512 + c4);
  }
  // out_W slice: 16 out-cols [q*16 .. q*16+16)
  for (int i = tid; i < 16*64; i += 256){
    int r = i >> 6, c4 = (i & 63) << 2;
    *(uint2*)(oWl + r*OWP + c4) = *(const uint2*)(oWh + (q*16 + r)*256 + c4);
  }
  __syncthreads();

  const int wv = tid >> 6;        // wave = gate (0:i 1:f 2:g 3:o)
  const int lane = tid & 63;
  const int lrow = lane & 15;
  const int lq = lane >> 4;
  const int arow = b_base + lrow; // A-fragment row (batch)

  const float bias0 = bih[(wv<<8) + j_base + lrow]      + bhh[(wv<<8) + j_base + lrow];
  const float bias1 = bih[(wv<<8) + j_base + 16 + lrow] + bhh[(wv<<8) + j_base + 16 + lrow];
  const float ob = outb[(q<<4) + lrow];

  float c0 = 0.f, c1 = 0.f;     // cell state, register-resident all 127 steps
  float lossAcc = 0.f;

  const f16* wb0 = Wl + ((wv<<5) + lrow)*KP + (lq<<3);
  const f16* wb1 = wb0 + 16*KP;

  // flag lines: producer q' of group gid owns flags[(gid*8+q')*FLAG_STRIDE].
  // wave 0 lanes poll the 8 producers via lane&7. Plain volatile (L2-coherent
  // within the XCD; same coherence domain the h data already uses).
  volatile unsigned int* pollflag =
      (volatile unsigned int*)(flags + ((gid<<3) + (lane & 7))*FLAG_STRIDE);
  volatile unsigned int* ourflag =
      (volatile unsigned int*)(flags + ((gid<<3) + q)*FLAG_STRIDE);

  for (int t = 0; t < NSTEP; ++t){
    f32x4 acc0 = {0.f,0.f,0.f,0.f}, acc1 = {0.f,0.f,0.f,0.f}, accL = {0.f,0.f,0.f,0.f};

    // ---- h-independent phase (runs while producers finish h(t)) ----
    const f16* xp = x_all + (((size_t)t*B_ + arow) << 8) + (lq << 3);
    const f16* gp = g_all + (((size_t)t*B_ + arow) << 8) + (lq << 3);
    half8 xr[8], gr[8];
#pragma unroll
    for (int kk = 0; kk < 8; ++kk) xr[kk] = *(const half8*)(xp + (kk<<5));
#pragma unroll
    for (int kk = 0; kk < 8; ++kk) gr[kk] = *(const half8*)(gp + (kk<<5));

    float vv[4], mm[4], dinvt = 0.f;
    if (wv == 0 && t > 0){
      dinvt = dinv[t];
#pragma unroll
      for (int r = 0; r < 4; ++r){
        size_t o = ((size_t)(b_base + (lq<<2) + r) << 14) + (t << 7) + (q<<4) + lrow;
        vv[r] = values[o]; mm[r] = masks[o];
      }
    }

    // x half (K = 0..255): consumed (and thus retired) before the poll/fence.
#pragma unroll
    for (int kk = 0; kk < 8; ++kk){
      half8 b0 = *(const half8*)(wb0 + (kk<<5));
      half8 b1 = *(const half8*)(wb1 + (kk<<5));
      acc0 = __builtin_amdgcn_mfma_f32_16x16x32_f16(xr[kk], b0, acc0, 0,0,0);
      acc1 = __builtin_amdgcn_mfma_f32_16x16x32_f16(xr[kk], b1, acc1, 0,0,0);
    }

    if (t > 0){
      // ---- wait for all 8 producers to publish h(t) ----
      if (wv == 0){
        int guard = 0;
        while (*pollflag < (unsigned)t && guard < 4000000){
          ++guard;
          __builtin_amdgcn_s_sleep(1);
        }
        // one CU-wide L1 invalidate; orders h_buf loads after the flags
        __builtin_amdgcn_fence(__ATOMIC_ACQUIRE, "agent");
      }
      __syncthreads();

      // h half (K = 256..511): A = h_t * gamma_t ; raw h feeds loss term t-1
      const f16* hp = h_buf + ((((t&1)*B_) + arow) << 8) + (lq << 3);
#pragma unroll
      for (int kk = 0; kk < 8; ++kk){
        half8 hr = *(const half8*)(hp + (kk<<5));
        if (wv == 0){
          half8 bo = *(const half8*)(oWl + lrow*OWP + (kk<<5) + (lq<<3));
          accL = __builtin_amdgcn_mfma_f32_16x16x32_f16(hr, bo, accL, 0,0,0);
        }
        half8 hg = hr * gr[kk];
        half8 b0 = *(const half8*)(wb0 + 256 + (kk<<5));
        half8 b1 = *(const half8*)(wb1 + 256 + (kk<<5));
        acc0 = __builtin_amdgcn_mfma_f32_16x16x32_f16(hg, b0, acc0, 0,0,0);
        acc1 = __builtin_amdgcn_mfma_f32_16x16x32_f16(hg, b1, acc1, 0,0,0);
      }
      if (wv == 0){
#pragma unroll
        for (int r = 0; r < 4; ++r){
          float ov = accL[r] + ob;
          lossAcc += fabsf(vv[r] - ov) * mm[r] * dinvt;
        }
      }
    }

    // publish gates to LDS (C layout: row=(lane>>4)*4+r, col=lane&15)
#pragma unroll
    for (int r = 0; r < 4; ++r){
      int row = (lq<<2) + r;
      gl[((wv<<4) + row)*33 + lrow]      = acc0[r] + bias0;
      gl[((wv<<4) + row)*33 + 16 + lrow] = acc1[r] + bias1;
    }
    __syncthreads();

    // cell update: 512 elems [16 rows x 32 cols], 2 per thread
#pragma unroll
    for (int pp = 0; pp < 2; ++pp){
      int e = tid + (pp<<8);
      int row = e >> 5, col = e & 31;
      float zi = gl[row*33 + col];
      float zf = gl[(16+row)*33 + col];
      float zg = gl[(32+row)*33 + col];
      float zo = gl[(48+row)*33 + col];
      float cp = pp ? c1 : c0;
      float cn = sigm(zf)*cp + sigm(zi)*tanh_(zg);
      float hn = sigm(zo)*tanh_(cn);
      if (pp) c1 = cn; else c0 = cn;
      int b = b_base + row, j = j_base + col;
      if (t < NSTEP-1){
        h_buf[((((t+1)&1)*B_ + b) << 8) + j] = (f16)hn;
      } else {
        d_out[(b<<8) + j] = hn;               // h, fp32 from registers
        d_out[(1<<17) + (b<<8) + j] = cn;     // c
      }
    }

    if (t < NSTEP-1){
      // __syncthreads drains vmcnt(0) for every wave -> all h stores of this
      // WG are in (same-XCD) L2 before tid0's flag store issues.
      __syncthreads();
      if (tid == 0) *ourflag = (unsigned)(t+1);
    }
  }

  // loss terms 0..125 reduction (wave 0 holds them)
  if (wv == 0){
#pragma unroll
    for (int off = 32; off > 0; off >>= 1)
      lossAcc += __shfl_down(lossAcc, off, 64);
    if (lane == 0) atomicAdd(loss_accum, lossAcc);
  }
}

// ---------------------------------------------------------------------------
__global__ __launch_bounds__(256) void kepi(
    const float* __restrict__ h_out, const float* __restrict__ outW,
    const float* __restrict__ outb, const float* __restrict__ values,
    const float* __restrict__ masks, float* __restrict__ num_final)
{
  int idx = blockIdx.x*256 + threadIdx.x;   // 65536 = 512*128
  int b = idx >> 7, f = idx & 127;
  const float* hr = h_out + (b << 8);
  const float* wr = outW + (f << 8);
  float s0 = 0.f, s1 = 0.f, s2 = 0.f, s3 = 0.f;
  for (int j = 0; j < 256; j += 4){
    s0 += hr[j]   * wr[j];
    s1 += hr[j+1] * wr[j+1];
    s2 += hr[j+2] * wr[j+2];
    s3 += hr[j+3] * wr[j+3];
  }
  float s = s0 + s1 + s2 + s3 + outb[f];
  size_t o = ((size_t)b << 14) + (127 << 7) + f;
  float term = fabsf(values[o] - s) * masks[o];
  __shared__ float red[256];
  red[threadIdx.x] = term; __syncthreads();
  for (int off = 128; off > 0; off >>= 1){
    if (threadIdx.x < off) red[threadIdx.x] += red[threadIdx.x + off];
    __syncthreads();
  }
  if (threadIdx.x == 0) atomicAdd(num_final, red[0]);
}

__global__ void kfin(const float* __restrict__ loss_accum,
                     const float* __restrict__ num_final,
                     const float* __restrict__ dinv, float* __restrict__ d_out)
{
  d_out[1<<18] = loss_accum[0] + num_final[0] * dinv[127];
}

// ---------------------------------------------------------------------------
extern "C" void kernel_launch(void* const* d_in, const int* in_sizes, int n_in,
                              void* d_out, int out_size, void* d_ws, size_t ws_size,
                              hipStream_t stream)
{
  const float* values = (const float*)d_in[0];
  const float* masks  = (const float*)d_in[1];
  const float* deltas = (const float*)d_in[2];
  const float* featW  = (const float*)d_in[3];
  const float* featb  = (const float*)d_in[4];
  const float* tempW  = (const float*)d_in[5];
  const float* tempb  = (const float*)d_in[6];
  const float* decW   = (const float*)d_in[7];
  const float* decb   = (const float*)d_in[8];
  const float* Wih    = (const float*)d_in[9];
  const float* Whh    = (const float*)d_in[10];
  const float* bih    = (const float*)d_in[11];
  const float* bhh    = (const float*)d_in[12];
  const float* outW   = (const float*)d_in[13];
  const float* outb   = (const float*)d_in[14];
  float* out = (float*)d_out;
  char* ws = (char*)d_ws;

  f16* Wt    = (f16*)(ws + 0);                 // 1 MB
  f16* oWh   = (f16*)(ws + 1048576);           // 64 KB
  f16* fWh   = (f16*)(ws + 1114112);           // 32 KB
  f16* tWh   = (f16*)(ws + 1146880);           // 32 KB
  f16* dWh   = (f16*)(ws + 1179648);           // 64 KB
  float* dinv = (float*)(ws + 1245184);        // 512 B
  unsigned int* flags = (unsigned int*)(ws + 1245696);  // 16 KB padded lines
  float* accums = (float*)(ws + 1262080);      // [0]=loss_accum [1]=num_final
  f16* h_buf = (f16*)(ws + 1262592);           // 512 KB ping-pong
  f16* x_all = (f16*)(ws + 2097152);           // 32 MB
  f16* g_all = (f16*)(ws + 35651584);          // 32 MB  (end ~66 MB)

  kprep<<<256, 256, 0, stream>>>(Wih, Whh, outW, featW, tempW, decW,
                                 Wt, oWh, fWh, tWh, dWh, flags, accums);
  kdenom<<<128, 256, 0, stream>>>(masks, dinv);

  const int S1 = 2 * 128 * PV * 2;   // V + Vt, 69632 B
  hipFuncSetAttribute((const void*)k1, hipFuncAttributeMaxDynamicSharedMemorySize, S1);
  k1<<<512, 256, S1, stream>>>(values, masks, fWh, tWh, featb, tempb, x_all);
  k2<<<512, 256, 0, stream>>>(deltas, dWh, decb, g_all);

  const int SLDS = 128*KP*2 + 16*OWP*2 + 64*33*4;   // 150016 B
  hipFuncSetAttribute((const void*)kscan, hipFuncAttributeMaxDynamicSharedMemorySize, SLDS);
  kscan<<<256, 256, SLDS, stream>>>(x_all, g_all, Wt, oWh, bih, bhh, outb,
                                    values, masks, dinv, h_buf, flags,
                                    accums, out);

  kepi<<<256, 256, 0, stream>>>(out, outW, outb, values, masks, accums + 1);
  kfin<<<1, 1, 0, stream>>>(accums, accums + 1, dinv, out);
}

// Round 6
// 1062.029 us; speedup vs baseline: 1.6173x; 1.0402x over previous
//
#include <hip/hip_runtime.h>

// ---------------------------------------------------------------------------
// Encoder: feature/temporal regression + temporal-decay LSTM scan + L1 loss
// B=512 T=128 F=128 H=256.  Outputs: h[512,256], c[512,256], loss (fp32).
//
// R5 -> R6: kscan restructured to a BARRIER-FREE wave-level scan.
//  Unit = wave: each wave owns 16 h-cols x all 4 gates (64 z-cols, K=512)
//  for its group's 16 batch rows. Holding all 4 gates per wave kills the
//  LDS gate exchange and ALL __syncthreads in the K-loop (R2-R5 had 2-3
//  barriers/step, each draining vmcnt across 4 skewed waves).
//  - W_hh B-frags (32 x half8 = 128 VGPR) + out_W loss frags in REGISTERS:
//    h-critical phase has zero ds_read. W_ih slice (128 KB) in LDS, only
//    touched in the h-independent x-phase (overlaps producer lag).
//  - Group = 4 WGs x 4 waves = 16 producer waves; per-wave monotone flag
//    line; poll via lanes (ballot); per-wave acquire fence; producer:
//    s_waitcnt vmcnt(0) + volatile flag store. Grid = 128 WGs (32 groups),
//    members ≡ gid mod 8 -> same XCD under SPX round-robin (validated R1-R5).
// ---------------------------------------------------------------------------

typedef _Float16 f16;
typedef _Float16 half8 __attribute__((ext_vector_type(8)));
typedef float f32x4 __attribute__((ext_vector_type(4)));

#define B_ 512
#define T_ 128
#define F_ 128
#define H_ 256
#define NSTEP 127
#define PV 136     // LDS row stride f16 for k1/k2 tiles
#define PW 264     // LDS row stride f16 for W_ih slice (528B: 16B-aligned, 2-way banks)
#define FLAG_STRIDE 16   // dwords: one 64B line per producer wave

__device__ __forceinline__ float sigm(float x){ return 1.f/(1.f + __expf(-x)); }
__device__ __forceinline__ float tanh_(float x){
  float e = __expf(-2.f*fabsf(x));
  float t = (1.f - e)/(1.f + e);
  return x >= 0.f ? t : -t;
}

// ---------------------------------------------------------------------------
__global__ void kprep(const float* __restrict__ Wih, const float* __restrict__ Whh,
                      const float* __restrict__ outW,
                      const float* __restrict__ featW, const float* __restrict__ tempW,
                      const float* __restrict__ decW,
                      f16* __restrict__ Wt, f16* __restrict__ oWh,
                      f16* __restrict__ fWh, f16* __restrict__ tWh,
                      f16* __restrict__ dWh, unsigned int* __restrict__ flags,
                      float* __restrict__ accums)
{
  int idx = blockIdx.x*256 + threadIdx.x;
  int stride = gridDim.x*256;
  // W_cat[zc][k]: k<256 -> W_ih[zc][k] (inp = [values_hat, masks]); k>=256 -> W_hh
  for (int i = idx; i < 1024*512; i += stride){
    int zc = i >> 9, k = i & 511;
    float w = (k < 256) ? Wih[zc*256 + k] : Whh[zc*256 + k - 256];
    Wt[i] = (f16)w;
  }
  for (int i = idx; i < 128*256; i += stride) oWh[i] = (f16)outW[i];
  // fWh[fo][gi] = feat_W[fo][gi], diag zeroed (B-frag layout)
  for (int i = idx; i < 128*128; i += stride){
    int fo = i >> 7, gi = i & 127;
    fWh[i] = (fo == gi) ? (f16)0.f : (f16)featW[i];
  }
  // tWh[t][s] = temp_W[t][s], diag zeroed (A-frag layout)
  for (int i = idx; i < 128*128; i += stride){
    int t = i >> 7, s = i & 127;
    tWh[i] = (s == t) ? (f16)0.f : (f16)tempW[i];
  }
  for (int i = idx; i < 256*128; i += stride) dWh[i] = (f16)decW[i];
  for (int i = idx; i < 512*FLAG_STRIDE; i += stride) flags[i] = 0u;
  if (idx < 2) accums[idx] = 0.f;
}

// ---------------------------------------------------------------------------
__global__ __launch_bounds__(256) void kdenom(const float* __restrict__ masks,
                                              float* __restrict__ dinv)
{
  int t = blockIdx.x;
  __shared__ float red[256];
  float s = 0.f;
  for (int i = threadIdx.x; i < B_*F_; i += 256){
    int b = i >> 7, f = i & 127;
    s += masks[((size_t)b << 14) + (t << 7) + f];
  }
  red[threadIdx.x] = s; __syncthreads();
  for (int o = 128; o > 0; o >>= 1){
    if (threadIdx.x < o) red[threadIdx.x] += red[threadIdx.x + o];
    __syncthreads();
  }
  if (threadIdx.x == 0) dinv[t] = 1.f/(red[0] + 1e-5f);
}

// ---------------------------------------------------------------------------
// k1 (MFMA): per batch b, C[t][f] = sum_g V[t][g]*featW[f][g](masked)
//                                  + sum_s tWm[t][s]*V[s][f]  + feat_b[f] + temp_b[t]
// x = (m!=0) ? v : C ; x_all[t][b][0:128]=x, [128:256]=m  (masks are exact 0/1)
__global__ __launch_bounds__(256) void k1(
    const float* __restrict__ values, const float* __restrict__ masks,
    const f16* __restrict__ fWh, const f16* __restrict__ tWh,
    const float* __restrict__ featb, const float* __restrict__ tempb,
    f16* __restrict__ x_all)
{
  extern __shared__ char sm1[];
  f16* V  = (f16*)sm1;                   // [128][PV]  row t, contig f
  f16* Vt = (f16*)(sm1 + 128*PV*2);      // [128][PV]  row f, contig t (transposed)
  const int b = blockIdx.x, tid = threadIdx.x;
  const float* vb = values + ((size_t)b << 14);

  for (int i = tid; i < 8192; i += 256){
    int f = i & 127, tp = i >> 7;      // tp = t/2
    float a = vb[(tp*2)*128 + f];
    float c = vb[(tp*2+1)*128 + f];
    f16 ha = (f16)a, hc = (f16)c;
    V[(tp*2)*PV + f]   = ha;
    V[(tp*2+1)*PV + f] = hc;
    union { f16 h[2]; unsigned u; } pk; pk.h[0] = ha; pk.h[1] = hc;
    *(unsigned*)(Vt + f*PV + tp*2) = pk.u;
  }
  __syncthreads();

  const int w = tid >> 6, lane = tid & 63, lrow = lane & 15, lq = lane >> 4;
  for (int ti2 = 0; ti2 < 2; ++ti2){
    const int t0 = (w*2 + ti2) << 4;
    half8 aV[4], aT[4];
#pragma unroll
    for (int kk = 0; kk < 4; ++kk){
      aV[kk] = *(const half8*)(V + (t0+lrow)*PV + kk*32 + lq*8);
      aT[kk] = *(const half8*)(tWh + (t0+lrow)*128 + kk*32 + lq*8);
    }
    float tb[4];
#pragma unroll
    for (int r = 0; r < 4; ++r) tb[r] = tempb[t0 + lq*4 + r];
#pragma unroll
    for (int fj = 0; fj < 8; ++fj){
      const int f0 = fj << 4;
      f32x4 acc = {0.f,0.f,0.f,0.f};
#pragma unroll
      for (int kk = 0; kk < 4; ++kk){
        half8 bF = *(const half8*)(fWh + (f0+lrow)*128 + kk*32 + lq*8);
        half8 bT = *(const half8*)(Vt  + (f0+lrow)*PV  + kk*32 + lq*8);
        acc = __builtin_amdgcn_mfma_f32_16x16x32_f16(aV[kk], bF, acc, 0,0,0);
        acc = __builtin_amdgcn_mfma_f32_16x16x32_f16(aT[kk], bT, acc, 0,0,0);
      }
      const float fb = featb[f0 + lrow];
#pragma unroll
      for (int r = 0; r < 4; ++r){
        int t = t0 + lq*4 + r, f = f0 + lrow;
        float vh = acc[r] + fb + tb[r];
        float v = (float)V[t*PV + f];
        float m = masks[((size_t)b << 14) + t*128 + f];
        float x = (m != 0.0f) ? v : vh;
        size_t o = (((size_t)t*B_ + b) << 8);
        x_all[o + f]       = (f16)x;
        x_all[o + 128 + f] = (f16)m;
      }
    }
  }
}

// ---------------------------------------------------------------------------
__global__ __launch_bounds__(256) void k2(
    const float* __restrict__ deltas, const f16* __restrict__ dWh,
    const float* __restrict__ decb, f16* __restrict__ g_all)
{
  __shared__ f16 D[128*PV];
  const int b = blockIdx.x, tid = threadIdx.x;
  const float* dp = deltas + ((size_t)b << 14);
  for (int i = tid; i < 8192; i += 256){
    int t = i >> 6, fd = (i & 63) << 1;
    float a = dp[t*128 + fd], c = dp[t*128 + fd + 1];
    union { f16 h[2]; unsigned u; } pk; pk.h[0] = (f16)a; pk.h[1] = (f16)c;
    *(unsigned*)(D + t*PV + fd) = pk.u;
  }
  __syncthreads();

  const int w = tid >> 6, lane = tid & 63, lrow = lane & 15, lq = lane >> 4;
  for (int ti2 = 0; ti2 < 2; ++ti2){
    const int t0 = (w*2 + ti2) << 4;
    half8 aD[4];
#pragma unroll
    for (int kk = 0; kk < 4; ++kk)
      aD[kk] = *(const half8*)(D + (t0+lrow)*PV + kk*32 + lq*8);
#pragma unroll
    for (int hj = 0; hj < 16; ++hj){
      const int h0 = hj << 4;
      f32x4 acc = {0.f,0.f,0.f,0.f};
#pragma unroll
      for (int kk = 0; kk < 4; ++kk){
        half8 bD = *(const half8*)(dWh + (h0+lrow)*128 + kk*32 + lq*8);
        acc = __builtin_amdgcn_mfma_f32_16x16x32_f16(aD[kk], bD, acc, 0,0,0);
      }
      const float db = decb[h0 + lrow];
#pragma unroll
      for (int r = 0; r < 4; ++r){
        int t = t0 + lq*4 + r, h = h0 + lrow;
        float gv = __expf(-fabsf(acc[r] + db));
        g_all[(((size_t)t*B_ + b) << 8) + h] = (f16)gv;
      }
    }
  }
}

// ---------------------------------------------------------------------------
// Barrier-free persistent scan. grid=128: gid=blockIdx&31 (16 batch rows),
// q=blockIdx>>5 in [0,4). Wave wv of WG q owns h-cols jcol=q*64+wv*16+[0,16)
// for ALL 4 gates -> cell update is wave-local, no LDS exchange, no barriers.
__global__ __launch_bounds__(256, 1) void kscan(
    const f16* __restrict__ x_all, const f16* __restrict__ g_all,
    const f16* __restrict__ Wt, const f16* __restrict__ oWh,
    const float* __restrict__ bih, const float* __restrict__ bhh,
    const float* __restrict__ outb,
    const float* __restrict__ values, const float* __restrict__ masks,
    const float* __restrict__ dinv,
    f16* __restrict__ h_buf, unsigned int* __restrict__ flags,
    float* __restrict__ loss_accum, float* __restrict__ d_out)
{
  extern __shared__ f16 Wl[];   // [256][PW]: W_ih rows for this WG's 256 z-cols

  const int tid = threadIdx.x;
  const int gid = blockIdx.x & 31;
  const int q   = blockIdx.x >> 5;
  const int b_base = gid << 4;
  const int wv = tid >> 6, lane = tid & 63, lrow = lane & 15, lq = lane >> 4;

  // stage W_ih slice: LDS row r = w*64 + g*16 + l  <->  zc = g*256 + q*64 + w*16 + l
  for (int i = tid; i < 256*32; i += 256){
    int r = i >> 5, seg = i & 31;
    int w = r >> 6, g = (r >> 4) & 3, l = r & 15;
    int zc = (g << 8) + (q << 6) + (w << 4) + l;
    *(uint4*)(Wl + r*PW + seg*8) = *(const uint4*)(Wt + zc*512 + seg*8);
  }
  __syncthreads();   // once, at startup only

  const int jcol = (q << 6) + (wv << 4) + lrow;   // this lane's h-col
  const int arow = b_base + lrow;                 // A-frag row (batch)

  // W_hh B-frags in registers: gate g, K-chunk kk (K=256..511 of Wt rows)
  half8 wh[4][8];
#pragma unroll
  for (int g = 0; g < 4; ++g)
#pragma unroll
    for (int kk = 0; kk < 8; ++kk)
      wh[g][kk] = *(const half8*)(Wt + ((g<<8) + jcol)*512 + 256 + kk*32 + (lq<<3));

  float bias[4];
#pragma unroll
  for (int g = 0; g < 4; ++g) bias[g] = bih[(g<<8) + jcol] + bhh[(g<<8) + jcol];

  // loss: waves 0,1 of each WG handle f-tile f0 = (q*2+wv)*16 (8 tiles total)
  const bool doLoss = (wv < 2);
  const int f0 = ((q<<1) + wv) << 4;
  half8 ow[8];
  float ob = 0.f;
  if (doLoss){
#pragma unroll
    for (int kk = 0; kk < 8; ++kk)
      ow[kk] = *(const half8*)(oWh + (f0+lrow)*256 + kk*32 + (lq<<3));
    ob = outb[f0 + lrow];
  }

  float c[4] = {0.f,0.f,0.f,0.f};
  float lossAcc = 0.f;

  // per-wave flag lines; lanes 0..15 (via lane&15) poll the 16 producer waves
  volatile const unsigned int* pollflag = flags + ((gid<<4) + lrow)*FLAG_STRIDE;
  volatile unsigned int* ourflag = flags + ((gid<<4) + (q<<2) + wv)*FLAG_STRIDE;

  for (int t = 0; t < NSTEP; ++t){
    // ---- h-independent phase ----
    const f16* xp = x_all + (((size_t)t*B_ + arow) << 8) + (lq << 3);
    const f16* gp = g_all + (((size_t)t*B_ + arow) << 8) + (lq << 3);
    half8 xr[8], gr[8];
#pragma unroll
    for (int kk = 0; kk < 8; ++kk) xr[kk] = *(const half8*)(xp + (kk<<5));
#pragma unroll
    for (int kk = 0; kk < 8; ++kk) gr[kk] = *(const half8*)(gp + (kk<<5));

    float vv[4], mm[4], dt = 0.f;
    if (doLoss && t > 0){
      dt = dinv[t];
#pragma unroll
      for (int r = 0; r < 4; ++r){
        size_t o = ((size_t)(b_base + (lq<<2) + r) << 14) + (t << 7) + f0 + lrow;
        vv[r] = values[o]; mm[r] = masks[o];
      }
    }

    f32x4 acc[4];
#pragma unroll
    for (int g = 0; g < 4; ++g){ acc[g][0]=bias[g]; acc[g][1]=bias[g]; acc[g][2]=bias[g]; acc[g][3]=bias[g]; }

    // x half (K=0..255), B-frags from LDS — off the h-critical chain
#pragma unroll
    for (int g = 0; g < 4; ++g){
      const f16* wb = Wl + ((wv<<6) + (g<<4) + lrow)*PW + (lq<<3);
#pragma unroll
      for (int kk = 0; kk < 8; ++kk){
        half8 bx = *(const half8*)(wb + (kk<<5));
        acc[g] = __builtin_amdgcn_mfma_f32_16x16x32_f16(xr[kk], bx, acc[g], 0,0,0);
      }
    }

    if (t > 0){
      // ---- wait for all 16 producer waves of this group ----
      int guard = 0;
      while (__ballot((int)(*pollflag < (unsigned)t)) != 0ull && guard < 4000000){
        ++guard;
        __builtin_amdgcn_s_sleep(1);
      }
      __builtin_amdgcn_fence(__ATOMIC_ACQUIRE, "agent");   // per-wave L1 inv

      // h half (K=256..511): register B-frags, zero ds_read on the chain
      const f16* hp = h_buf + ((((t&1)*B_) + arow) << 8) + (lq << 3);
      half8 hr[8];
#pragma unroll
      for (int kk = 0; kk < 8; ++kk) hr[kk] = *(const half8*)(hp + (kk<<5));

      f32x4 accL = {0.f,0.f,0.f,0.f};
      if (doLoss){
#pragma unroll
        for (int kk = 0; kk < 8; ++kk)
          accL = __builtin_amdgcn_mfma_f32_16x16x32_f16(hr[kk], ow[kk], accL, 0,0,0);
      }
#pragma unroll
      for (int kk = 0; kk < 8; ++kk){
        half8 hg = hr[kk] * gr[kk];
#pragma unroll
        for (int g = 0; g < 4; ++g)
          acc[g] = __builtin_amdgcn_mfma_f32_16x16x32_f16(hg, wh[g][kk], acc[g], 0,0,0);
      }
      if (doLoss){
#pragma unroll
        for (int r = 0; r < 4; ++r)
          lossAcc += fabsf(vv[r] - (accL[r] + ob)) * mm[r] * dt;
      }
    }

    // ---- cell update: wave-local, 4 elems/lane (b = b_base+lq*4+r, j = jcol) ----
#pragma unroll
    for (int r = 0; r < 4; ++r){
      float zi = acc[0][r], zf = acc[1][r], zg = acc[2][r], zo = acc[3][r];
      float cn = sigm(zf)*c[r] + sigm(zi)*tanh_(zg);
      float hn = sigm(zo)*tanh_(cn);
      c[r] = cn;
      int b = b_base + (lq<<2) + r;
      if (t < NSTEP-1){
        h_buf[((((t+1)&1)*B_ + b) << 8) + jcol] = (f16)hn;
      } else {
        d_out[(b<<8) + jcol] = hn;               // h
        d_out[(1<<17) + (b<<8) + jcol] = cn;     // c
      }
    }

    if (t < NSTEP-1){
      // all this wave's h stores retired (write-through L1 -> in L2), then flag
      asm volatile("s_waitcnt vmcnt(0)" ::: "memory");
      if (lane == 0) *ourflag = (unsigned)(t+1);
    }
  }

  if (doLoss){
#pragma unroll
    for (int off = 32; off > 0; off >>= 1)
      lossAcc += __shfl_down(lossAcc, off, 64);
    if (lane == 0) atomicAdd(loss_accum, lossAcc);
  }
}

// ---------------------------------------------------------------------------
__global__ __launch_bounds__(256) void kepi(
    const float* __restrict__ h_out, const float* __restrict__ outW,
    const float* __restrict__ outb, const float* __restrict__ values,
    const float* __restrict__ masks, float* __restrict__ num_final)
{
  int idx = blockIdx.x*256 + threadIdx.x;   // 65536 = 512*128
  int b = idx >> 7, f = idx & 127;
  const float* hr = h_out + (b << 8);
  const float* wr = outW + (f << 8);
  float s0 = 0.f, s1 = 0.f, s2 = 0.f, s3 = 0.f;
  for (int j = 0; j < 256; j += 4){
    s0 += hr[j]   * wr[j];
    s1 += hr[j+1] * wr[j+1];
    s2 += hr[j+2] * wr[j+2];
    s3 += hr[j+3] * wr[j+3];
  }
  float s = s0 + s1 + s2 + s3 + outb[f];
  size_t o = ((size_t)b << 14) + (127 << 7) + f;
  float term = fabsf(values[o] - s) * masks[o];
  __shared__ float red[256];
  red[threadIdx.x] = term; __syncthreads();
  for (int off = 128; off > 0; off >>= 1){
    if (threadIdx.x < off) red[threadIdx.x] += red[threadIdx.x + off];
    __syncthreads();
  }
  if (threadIdx.x == 0) atomicAdd(num_final, red[0]);
}

__global__ void kfin(const float* __restrict__ loss_accum,
                     const float* __restrict__ num_final,
                     const float* __restrict__ dinv, float* __restrict__ d_out)
{
  d_out[1<<18] = loss_accum[0] + num_final[0] * dinv[127];
}

// ---------------------------------------------------------------------------
extern "C" void kernel_launch(void* const* d_in, const int* in_sizes, int n_in,
                              void* d_out, int out_size, void* d_ws, size_t ws_size,
                              hipStream_t stream)
{
  const float* values = (const float*)d_in[0];
  const float* masks  = (const float*)d_in[1];
  const float* deltas = (const float*)d_in[2];
  const float* featW  = (const float*)d_in[3];
  const float* featb  = (const float*)d_in[4];
  const float* tempW  = (const float*)d_in[5];
  const float* tempb  = (const float*)d_in[6];
  const float* decW   = (const float*)d_in[7];
  const float* decb   = (const float*)d_in[8];
  const float* Wih    = (const float*)d_in[9];
  const float* Whh    = (const float*)d_in[10];
  const float* bih    = (const float*)d_in[11];
  const float* bhh    = (const float*)d_in[12];
  const float* outW   = (const float*)d_in[13];
  const float* outb   = (const float*)d_in[14];
  float* out = (float*)d_out;
  char* ws = (char*)d_ws;

  f16* Wt    = (f16*)(ws + 0);                 // 1 MB
  f16* oWh   = (f16*)(ws + 1048576);           // 64 KB
  f16* fWh   = (f16*)(ws + 1114112);           // 32 KB
  f16* tWh   = (f16*)(ws + 1146880);           // 32 KB
  f16* dWh   = (f16*)(ws + 1179648);           // 64 KB
  float* dinv = (float*)(ws + 1245184);        // 512 B
  unsigned int* flags = (unsigned int*)(ws + 1245696);  // 32 KB padded lines
  float* accums = (float*)(ws + 1278464);      // [0]=loss_accum [1]=num_final
  f16* h_buf = (f16*)(ws + 1278976);           // 512 KB ping-pong
  f16* x_all = (f16*)(ws + 2097152);           // 32 MB
  f16* g_all = (f16*)(ws + 35651584);          // 32 MB  (end ~66 MB)

  kprep<<<256, 256, 0, stream>>>(Wih, Whh, outW, featW, tempW, decW,
                                 Wt, oWh, fWh, tWh, dWh, flags, accums);
  kdenom<<<128, 256, 0, stream>>>(masks, dinv);

  const int S1 = 2 * 128 * PV * 2;   // V + Vt, 69632 B
  hipFuncSetAttribute((const void*)k1, hipFuncAttributeMaxDynamicSharedMemorySize, S1);
  k1<<<512, 256, S1, stream>>>(values, masks, fWh, tWh, featb, tempb, x_all);
  k2<<<512, 256, 0, stream>>>(deltas, dWh, decb, g_all);

  const int SLDS = 256 * PW * 2;   // 135168 B
  hipFuncSetAttribute((const void*)kscan, hipFuncAttributeMaxDynamicSharedMemorySize, SLDS);
  kscan<<<128, 256, SLDS, stream>>>(x_all, g_all, Wt, oWh, bih, bhh, outb,
                                    values, masks, dinv, h_buf, flags,
                                    accums, out);

  kepi<<<256, 256, 0, stream>>>(out, outW, outb, values, masks, accums + 1);
  kfin<<<1, 1, 0, stream>>>(accums, accums + 1, dinv, out);
}

// Round 7
// 1061.829 us; speedup vs baseline: 1.6176x; 1.0002x over previous
//
#include <hip/hip_runtime.h>

// ---------------------------------------------------------------------------
// Encoder: feature/temporal regression + temporal-decay LSTM scan + L1 loss
// B=512 T=128 F=128 H=256.  Outputs: h[512,256], c[512,256], loss (fp32).
//
// R6 -> R7: SCLK-throttle experiment. Scan dataflow is byte-identical to R6
// (barrier-free wave-level scan). Changes:
//  1. Busy-poll: s_sleep removed from poll loops (a sleeping wave leaves its
//     SIMD 100% idle -> SMU sees a ~3%-active chip and drops SCLK; all six
//     prior rounds pinned at ~6 us/step despite structural rewrites, i.e. an
//     external rate limiter).
//  2. Heater WGs: grid=256; blocks 128..255 spin dense dependent FMAs until
//     a done-counter (32 group completions) fires, keeping every CU active.
//     256 WGs x 1 WG/CU are co-resident (as R1-R5), so heaters cannot
//     starve scan WGs.
// ---------------------------------------------------------------------------

typedef _Float16 f16;
typedef _Float16 half8 __attribute__((ext_vector_type(8)));
typedef float f32x4 __attribute__((ext_vector_type(4)));

#define B_ 512
#define T_ 128
#define F_ 128
#define H_ 256
#define NSTEP 127
#define PV 136     // LDS row stride f16 for k1/k2 tiles
#define PW 264     // LDS row stride f16 for W_ih slice
#define FLAG_STRIDE 16   // dwords: one 64B line per producer wave
#define DONE_LINE (511*FLAG_STRIDE)

__device__ __forceinline__ float sigm(float x){ return 1.f/(1.f + __expf(-x)); }
__device__ __forceinline__ float tanh_(float x){
  float e = __expf(-2.f*fabsf(x));
  float t = (1.f - e)/(1.f + e);
  return x >= 0.f ? t : -t;
}

// ---------------------------------------------------------------------------
__global__ void kprep(const float* __restrict__ Wih, const float* __restrict__ Whh,
                      const float* __restrict__ outW,
                      const float* __restrict__ featW, const float* __restrict__ tempW,
                      const float* __restrict__ decW,
                      f16* __restrict__ Wt, f16* __restrict__ oWh,
                      f16* __restrict__ fWh, f16* __restrict__ tWh,
                      f16* __restrict__ dWh, unsigned int* __restrict__ flags,
                      float* __restrict__ accums)
{
  int idx = blockIdx.x*256 + threadIdx.x;
  int stride = gridDim.x*256;
  // W_cat[zc][k]: k<256 -> W_ih[zc][k] (inp = [values_hat, masks]); k>=256 -> W_hh
  for (int i = idx; i < 1024*512; i += stride){
    int zc = i >> 9, k = i & 511;
    float w = (k < 256) ? Wih[zc*256 + k] : Whh[zc*256 + k - 256];
    Wt[i] = (f16)w;
  }
  for (int i = idx; i < 128*256; i += stride) oWh[i] = (f16)outW[i];
  // fWh[fo][gi] = feat_W[fo][gi], diag zeroed (B-frag layout)
  for (int i = idx; i < 128*128; i += stride){
    int fo = i >> 7, gi = i & 127;
    fWh[i] = (fo == gi) ? (f16)0.f : (f16)featW[i];
  }
  // tWh[t][s] = temp_W[t][s], diag zeroed (A-frag layout)
  for (int i = idx; i < 128*128; i += stride){
    int t = i >> 7, s = i & 127;
    tWh[i] = (s == t) ? (f16)0.f : (f16)tempW[i];
  }
  for (int i = idx; i < 256*128; i += stride) dWh[i] = (f16)decW[i];
  for (int i = idx; i < 512*FLAG_STRIDE; i += stride) flags[i] = 0u;
  if (idx < 2) accums[idx] = 0.f;
}

// ---------------------------------------------------------------------------
__global__ __launch_bounds__(256) void kdenom(const float* __restrict__ masks,
                                              float* __restrict__ dinv)
{
  int t = blockIdx.x;
  __shared__ float red[256];
  float s = 0.f;
  for (int i = threadIdx.x; i < B_*F_; i += 256){
    int b = i >> 7, f = i & 127;
    s += masks[((size_t)b << 14) + (t << 7) + f];
  }
  red[threadIdx.x] = s; __syncthreads();
  for (int o = 128; o > 0; o >>= 1){
    if (threadIdx.x < o) red[threadIdx.x] += red[threadIdx.x + o];
    __syncthreads();
  }
  if (threadIdx.x == 0) dinv[t] = 1.f/(red[0] + 1e-5f);
}

// ---------------------------------------------------------------------------
// k1 (MFMA): per batch b, C[t][f] = sum_g V[t][g]*featW[f][g](masked)
//                                  + sum_s tWm[t][s]*V[s][f]  + feat_b[f] + temp_b[t]
// x = (m!=0) ? v : C ; x_all[t][b][0:128]=x, [128:256]=m  (masks are exact 0/1)
__global__ __launch_bounds__(256) void k1(
    const float* __restrict__ values, const float* __restrict__ masks,
    const f16* __restrict__ fWh, const f16* __restrict__ tWh,
    const float* __restrict__ featb, const float* __restrict__ tempb,
    f16* __restrict__ x_all)
{
  extern __shared__ char sm1[];
  f16* V  = (f16*)sm1;                   // [128][PV]  row t, contig f
  f16* Vt = (f16*)(sm1 + 128*PV*2);      // [128][PV]  row f, contig t (transposed)
  const int b = blockIdx.x, tid = threadIdx.x;
  const float* vb = values + ((size_t)b << 14);

  for (int i = tid; i < 8192; i += 256){
    int f = i & 127, tp = i >> 7;      // tp = t/2
    float a = vb[(tp*2)*128 + f];
    float c = vb[(tp*2+1)*128 + f];
    f16 ha = (f16)a, hc = (f16)c;
    V[(tp*2)*PV + f]   = ha;
    V[(tp*2+1)*PV + f] = hc;
    union { f16 h[2]; unsigned u; } pk; pk.h[0] = ha; pk.h[1] = hc;
    *(unsigned*)(Vt + f*PV + tp*2) = pk.u;
  }
  __syncthreads();

  const int w = tid >> 6, lane = tid & 63, lrow = lane & 15, lq = lane >> 4;
  for (int ti2 = 0; ti2 < 2; ++ti2){
    const int t0 = (w*2 + ti2) << 4;
    half8 aV[4], aT[4];
#pragma unroll
    for (int kk = 0; kk < 4; ++kk){
      aV[kk] = *(const half8*)(V + (t0+lrow)*PV + kk*32 + lq*8);
      aT[kk] = *(const half8*)(tWh + (t0+lrow)*128 + kk*32 + lq*8);
    }
    float tb[4];
#pragma unroll
    for (int r = 0; r < 4; ++r) tb[r] = tempb[t0 + lq*4 + r];
#pragma unroll
    for (int fj = 0; fj < 8; ++fj){
      const int f0 = fj << 4;
      f32x4 acc = {0.f,0.f,0.f,0.f};
#pragma unroll
      for (int kk = 0; kk < 4; ++kk){
        half8 bF = *(const half8*)(fWh + (f0+lrow)*128 + kk*32 + lq*8);
        half8 bT = *(const half8*)(Vt  + (f0+lrow)*PV  + kk*32 + lq*8);
        acc = __builtin_amdgcn_mfma_f32_16x16x32_f16(aV[kk], bF, acc, 0,0,0);
        acc = __builtin_amdgcn_mfma_f32_16x16x32_f16(aT[kk], bT, acc, 0,0,0);
      }
      const float fb = featb[f0 + lrow];
#pragma unroll
      for (int r = 0; r < 4; ++r){
        int t = t0 + lq*4 + r, f = f0 + lrow;
        float vh = acc[r] + fb + tb[r];
        float v = (float)V[t*PV + f];
        float m = masks[((size_t)b << 14) + t*128 + f];
        float x = (m != 0.0f) ? v : vh;
        size_t o = (((size_t)t*B_ + b) << 8);
        x_all[o + f]       = (f16)x;
        x_all[o + 128 + f] = (f16)m;
      }
    }
  }
}

// ---------------------------------------------------------------------------
__global__ __launch_bounds__(256) void k2(
    const float* __restrict__ deltas, const f16* __restrict__ dWh,
    const float* __restrict__ decb, f16* __restrict__ g_all)
{
  __shared__ f16 D[128*PV];
  const int b = blockIdx.x, tid = threadIdx.x;
  const float* dp = deltas + ((size_t)b << 14);
  for (int i = tid; i < 8192; i += 256){
    int t = i >> 6, fd = (i & 63) << 1;
    float a = dp[t*128 + fd], c = dp[t*128 + fd + 1];
    union { f16 h[2]; unsigned u; } pk; pk.h[0] = (f16)a; pk.h[1] = (f16)c;
    *(unsigned*)(D + t*PV + fd) = pk.u;
  }
  __syncthreads();

  const int w = tid >> 6, lane = tid & 63, lrow = lane & 15, lq = lane >> 4;
  for (int ti2 = 0; ti2 < 2; ++ti2){
    const int t0 = (w*2 + ti2) << 4;
    half8 aD[4];
#pragma unroll
    for (int kk = 0; kk < 4; ++kk)
      aD[kk] = *(const half8*)(D + (t0+lrow)*PV + kk*32 + lq*8);
#pragma unroll
    for (int hj = 0; hj < 16; ++hj){
      const int h0 = hj << 4;
      f32x4 acc = {0.f,0.f,0.f,0.f};
#pragma unroll
      for (int kk = 0; kk < 4; ++kk){
        half8 bD = *(const half8*)(dWh + (h0+lrow)*128 + kk*32 + lq*8);
        acc = __builtin_amdgcn_mfma_f32_16x16x32_f16(aD[kk], bD, acc, 0,0,0);
      }
      const float db = decb[h0 + lrow];
#pragma unroll
      for (int r = 0; r < 4; ++r){
        int t = t0 + lq*4 + r, h = h0 + lrow;
        float gv = __expf(-fabsf(acc[r] + db));
        g_all[(((size_t)t*B_ + b) << 8) + h] = (f16)gv;
      }
    }
  }
}

// ---------------------------------------------------------------------------
// Barrier-free persistent scan (R6 dataflow). Blocks 0..127: scan (gid =
// blockIdx&31, q = blockIdx>>5). Blocks 128..255: heaters — dense FMA spin
// until all 32 groups signal done (keeps SCLK up; co-resident by 1 WG/CU).
__global__ __launch_bounds__(256, 1) void kscan(
    const f16* __restrict__ x_all, const f16* __restrict__ g_all,
    const f16* __restrict__ Wt, const f16* __restrict__ oWh,
    const float* __restrict__ bih, const float* __restrict__ bhh,
    const float* __restrict__ outb,
    const float* __restrict__ values, const float* __restrict__ masks,
    const float* __restrict__ dinv,
    f16* __restrict__ h_buf, unsigned int* __restrict__ flags,
    float* __restrict__ loss_accum, float* __restrict__ d_out)
{
  extern __shared__ f16 Wl[];   // [256][PW]: W_ih rows for this WG's 256 z-cols

  volatile unsigned int* doneline = (volatile unsigned int*)(flags + DONE_LINE);
  if (blockIdx.x >= 128){
    // ---- heater: keep the CU's SIMDs issuing until the scan completes ----
    float a = 1.0f + threadIdx.x * 1e-3f;
    int guard = 0;
    while (*doneline < 32u && guard < 200000){
      ++guard;
#pragma unroll
      for (int i = 0; i < 128; ++i) a = __builtin_fmaf(a, 1.0000001f, 1e-7f);
    }
    if (a < 0.f)   // never true; keeps the FMA chain live
      *((volatile float*)(flags + 504*FLAG_STRIDE)) = a;
    return;
  }

  const int tid = threadIdx.x;
  const int gid = blockIdx.x & 31;
  const int q   = blockIdx.x >> 5;
  const int b_base = gid << 4;
  const int wv = tid >> 6, lane = tid & 63, lrow = lane & 15, lq = lane >> 4;

  // stage W_ih slice: LDS row r = w*64 + g*16 + l  <->  zc = g*256 + q*64 + w*16 + l
  for (int i = tid; i < 256*32; i += 256){
    int r = i >> 5, seg = i & 31;
    int w = r >> 6, g = (r >> 4) & 3, l = r & 15;
    int zc = (g << 8) + (q << 6) + (w << 4) + l;
    *(uint4*)(Wl + r*PW + seg*8) = *(const uint4*)(Wt + zc*512 + seg*8);
  }
  __syncthreads();   // once, at startup only

  const int jcol = (q << 6) + (wv << 4) + lrow;   // this lane's h-col
  const int arow = b_base + lrow;                 // A-frag row (batch)

  // W_hh B-frags in registers: gate g, K-chunk kk (K=256..511 of Wt rows)
  half8 wh[4][8];
#pragma unroll
  for (int g = 0; g < 4; ++g)
#pragma unroll
    for (int kk = 0; kk < 8; ++kk)
      wh[g][kk] = *(const half8*)(Wt + ((g<<8) + jcol)*512 + 256 + kk*32 + (lq<<3));

  float bias[4];
#pragma unroll
  for (int g = 0; g < 4; ++g) bias[g] = bih[(g<<8) + jcol] + bhh[(g<<8) + jcol];

  // loss: waves 0,1 of each WG handle f-tile f0 = (q*2+wv)*16 (8 tiles total)
  const bool doLoss = (wv < 2);
  const int f0 = ((q<<1) + wv) << 4;
  half8 ow[8];
  float ob = 0.f;
  if (doLoss){
#pragma unroll
    for (int kk = 0; kk < 8; ++kk)
      ow[kk] = *(const half8*)(oWh + (f0+lrow)*256 + kk*32 + (lq<<3));
    ob = outb[f0 + lrow];
  }

  float c[4] = {0.f,0.f,0.f,0.f};
  float lossAcc = 0.f;

  // per-wave flag lines; lanes (lane&15) poll the 16 producer waves
  volatile const unsigned int* pollflag = flags + ((gid<<4) + lrow)*FLAG_STRIDE;
  volatile unsigned int* ourflag = flags + ((gid<<4) + (q<<2) + wv)*FLAG_STRIDE;

  for (int t = 0; t < NSTEP; ++t){
    // ---- h-independent phase ----
    const f16* xp = x_all + (((size_t)t*B_ + arow) << 8) + (lq << 3);
    const f16* gp = g_all + (((size_t)t*B_ + arow) << 8) + (lq << 3);
    half8 xr[8], gr[8];
#pragma unroll
    for (int kk = 0; kk < 8; ++kk) xr[kk] = *(const half8*)(xp + (kk<<5));
#pragma unroll
    for (int kk = 0; kk < 8; ++kk) gr[kk] = *(const half8*)(gp + (kk<<5));

    float vv[4], mm[4], dt = 0.f;
    if (doLoss && t > 0){
      dt = dinv[t];
#pragma unroll
      for (int r = 0; r < 4; ++r){
        size_t o = ((size_t)(b_base + (lq<<2) + r) << 14) + (t << 7) + f0 + lrow;
        vv[r] = values[o]; mm[r] = masks[o];
      }
    }

    f32x4 acc[4];
#pragma unroll
    for (int g = 0; g < 4; ++g){ acc[g][0]=bias[g]; acc[g][1]=bias[g]; acc[g][2]=bias[g]; acc[g][3]=bias[g]; }

    // x half (K=0..255), B-frags from LDS — off the h-critical chain
#pragma unroll
    for (int g = 0; g < 4; ++g){
      const f16* wb = Wl + ((wv<<6) + (g<<4) + lrow)*PW + (lq<<3);
#pragma unroll
      for (int kk = 0; kk < 8; ++kk){
        half8 bx = *(const half8*)(wb + (kk<<5));
        acc[g] = __builtin_amdgcn_mfma_f32_16x16x32_f16(xr[kk], bx, acc[g], 0,0,0);
      }
    }

    if (t > 0){
      // ---- busy-wait for all 16 producer waves of this group ----
      int guard = 0;
      while (__ballot((int)(*pollflag < (unsigned)t)) != 0ull && guard < 4000000)
        ++guard;
      __builtin_amdgcn_fence(__ATOMIC_ACQUIRE, "agent");   // per-wave L1 inv

      // h half (K=256..511): register B-frags, zero ds_read on the chain
      const f16* hp = h_buf + ((((t&1)*B_) + arow) << 8) + (lq << 3);
      half8 hr[8];
#pragma unroll
      for (int kk = 0; kk < 8; ++kk) hr[kk] = *(const half8*)(hp + (kk<<5));

      f32x4 accL = {0.f,0.f,0.f,0.f};
      if (doLoss){
#pragma unroll
        for (int kk = 0; kk < 8; ++kk)
          accL = __builtin_amdgcn_mfma_f32_16x16x32_f16(hr[kk], ow[kk], accL, 0,0,0);
      }
#pragma unroll
      for (int kk = 0; kk < 8; ++kk){
        half8 hg = hr[kk] * gr[kk];
#pragma unroll
        for (int g = 0; g < 4; ++g)
          acc[g] = __builtin_amdgcn_mfma_f32_16x16x32_f16(hg, wh[g][kk], acc[g], 0,0,0);
      }
      if (doLoss){
#pragma unroll
        for (int r = 0; r < 4; ++r)
          lossAcc += fabsf(vv[r] - (accL[r] + ob)) * mm[r] * dt;
      }
    }

    // ---- cell update: wave-local, 4 elems/lane (b = b_base+lq*4+r, j = jcol) ----
#pragma unroll
    for (int r = 0; r < 4; ++r){
      float zi = acc[0][r], zf = acc[1][r], zg = acc[2][r], zo = acc[3][r];
      float cn = sigm(zf)*c[r] + sigm(zi)*tanh_(zg);
      float hn = sigm(zo)*tanh_(cn);
      c[r] = cn;
      int b = b_base + (lq<<2) + r;
      if (t < NSTEP-1){
        h_buf[((((t+1)&1)*B_ + b) << 8) + jcol] = (f16)hn;
      } else {
        d_out[(b<<8) + jcol] = hn;               // h
        d_out[(1<<17) + (b<<8) + jcol] = cn;     // c
      }
    }

    if (t < NSTEP-1){
      // all this wave's h stores retired (write-through L1 -> in L2), then flag
      asm volatile("s_waitcnt vmcnt(0)" ::: "memory");
      if (lane == 0) *ourflag = (unsigned)(t+1);
    }
  }

  // signal group completion (heater exit): one lane per group
  if (q == 0 && wv == 0 && lane == 0)
    __hip_atomic_fetch_add((unsigned int*)(flags + DONE_LINE), 1u,
                           __ATOMIC_RELAXED, __HIP_MEMORY_SCOPE_AGENT);

  if (doLoss){
#pragma unroll
    for (int off = 32; off > 0; off >>= 1)
      lossAcc += __shfl_down(lossAcc, off, 64);
    if (lane == 0) atomicAdd(loss_accum, lossAcc);
  }
}

// ---------------------------------------------------------------------------
__global__ __launch_bounds__(256) void kepi(
    const float* __restrict__ h_out, const float* __restrict__ outW,
    const float* __restrict__ outb, const float* __restrict__ values,
    const float* __restrict__ masks, float* __restrict__ num_final)
{
  int idx = blockIdx.x*256 + threadIdx.x;   // 65536 = 512*128
  int b = idx >> 7, f = idx & 127;
  const float* hr = h_out + (b << 8);
  const float* wr = outW + (f << 8);
  float s0 = 0.f, s1 = 0.f, s2 = 0.f, s3 = 0.f;
  for (int j = 0; j < 256; j += 4){
    s0 += hr[j]   * wr[j];
    s1 += hr[j+1] * wr[j+1];
    s2 += hr[j+2] * wr[j+2];
    s3 += hr[j+3] * wr[j+3];
  }
  float s = s0 + s1 + s2 + s3 + outb[f];
  size_t o = ((size_t)b << 14) + (127 << 7) + f;
  float term = fabsf(values[o] - s) * masks[o];
  __shared__ float red[256];
  red[threadIdx.x] = term; __syncthreads();
  for (int off = 128; off > 0; off >>= 1){
    if (threadIdx.x < off) red[threadIdx.x] += red[threadIdx.x + off];
    __syncthreads();
  }
  if (threadIdx.x == 0) atomicAdd(num_final, red[0]);
}

__global__ void kfin(const float* __restrict__ loss_accum,
                     const float* __restrict__ num_final,
                     const float* __restrict__ dinv, float* __restrict__ d_out)
{
  d_out[1<<18] = loss_accum[0] + num_final[0] * dinv[127];
}

// ---------------------------------------------------------------------------
extern "C" void kernel_launch(void* const* d_in, const int* in_sizes, int n_in,
                              void* d_out, int out_size, void* d_ws, size_t ws_size,
                              hipStream_t stream)
{
  const float* values = (const float*)d_in[0];
  const float* masks  = (const float*)d_in[1];
  const float* deltas = (const float*)d_in[2];
  const float* featW  = (const float*)d_in[3];
  const float* featb  = (const float*)d_in[4];
  const float* tempW  = (const float*)d_in[5];
  const float* tempb  = (const float*)d_in[6];
  const float* decW   = (const float*)d_in[7];
  const float* decb   = (const float*)d_in[8];
  const float* Wih    = (const float*)d_in[9];
  const float* Whh    = (const float*)d_in[10];
  const float* bih    = (const float*)d_in[11];
  const float* bhh    = (const float*)d_in[12];
  const float* outW   = (const float*)d_in[13];
  const float* outb   = (const float*)d_in[14];
  float* out = (float*)d_out;
  char* ws = (char*)d_ws;

  f16* Wt    = (f16*)(ws + 0);                 // 1 MB
  f16* oWh   = (f16*)(ws + 1048576);           // 64 KB
  f16* fWh   = (f16*)(ws + 1114112);           // 32 KB
  f16* tWh   = (f16*)(ws + 1146880);           // 32 KB
  f16* dWh   = (f16*)(ws + 1179648);           // 64 KB
  float* dinv = (float*)(ws + 1245184);        // 512 B
  unsigned int* flags = (unsigned int*)(ws + 1245696);  // 32 KB padded lines
  float* accums = (float*)(ws + 1278464);      // [0]=loss_accum [1]=num_final
  f16* h_buf = (f16*)(ws + 1278976);           // 512 KB ping-pong
  f16* x_all = (f16*)(ws + 2097152);           // 32 MB
  f16* g_all = (f16*)(ws + 35651584);          // 32 MB  (end ~66 MB)

  kprep<<<256, 256, 0, stream>>>(Wih, Whh, outW, featW, tempW, decW,
                                 Wt, oWh, fWh, tWh, dWh, flags, accums);
  kdenom<<<128, 256, 0, stream>>>(masks, dinv);

  const int S1 = 2 * 128 * PV * 2;   // V + Vt, 69632 B
  hipFuncSetAttribute((const void*)k1, hipFuncAttributeMaxDynamicSharedMemorySize, S1);
  k1<<<512, 256, S1, stream>>>(values, masks, fWh, tWh, featb, tempb, x_all);
  k2<<<512, 256, 0, stream>>>(deltas, dWh, decb, g_all);

  const int SLDS = 256 * PW * 2;   // 135168 B
  hipFuncSetAttribute((const void*)kscan, hipFuncAttributeMaxDynamicSharedMemorySize, SLDS);
  kscan<<<256, 256, SLDS, stream>>>(x_all, g_all, Wt, oWh, bih, bhh, outb,
                                    values, masks, dinv, h_buf, flags,
                                    accums, out);

  kepi<<<256, 256, 0, stream>>>(out, outW, outb, values, masks, accums + 1);
  kfin<<<1, 1, 0, stream>>>(accums, accums + 1, dinv, out);
}